// Round 4
// baseline (185.259 us; speedup 1.0000x reference)
//
#include <hip/hip_runtime.h>

// ---- problem constants ----
#define T_SEQ 2048
#define D_MODEL 1024
#define N_HEADS 16
#define D_HEAD 64
#define NT 32          // T_SEQ / 64
#define K_DIM 1024

typedef __attribute__((ext_vector_type(8))) __bf16 bf16x8;
typedef __attribute__((ext_vector_type(4))) __bf16 bf16x4;
typedef __attribute__((ext_vector_type(2))) __bf16 bf16x2;
typedef __attribute__((ext_vector_type(4))) float f32x4;

#define SCL_LOG2 0.180336880f  // 0.125 * log2(e)
#define MASKVAL (-1e30f)

#define GLOAD_LDS16(g, l)                                                     \
  __builtin_amdgcn_global_load_lds(                                           \
      (const __attribute__((address_space(1))) void*)(g),                     \
      (__attribute__((address_space(3))) void*)(l), 16, 0, 0)

// ---------------- f32 -> bf16 convert ----------------
__global__ __launch_bounds__(256) void cvt_f32_bf16(const float* __restrict__ in,
                                                    __bf16* __restrict__ out, int n4) {
  int i = blockIdx.x * 256 + threadIdx.x;
  if (i >= n4) return;
  float4 f = reinterpret_cast<const float4*>(in)[i];
  bf16x4 o;
  o[0] = (__bf16)f.x; o[1] = (__bf16)f.y; o[2] = (__bf16)f.z; o[3] = (__bf16)f.w;
  reinterpret_cast<bf16x4*>(out)[i] = o;
}

// ---------------- QKV GEMM (m97 structure): C = A @ W^T + bias, scatter ----------------
__global__ __launch_bounds__(256) void gemm_qkv(
    const __bf16* __restrict__ A, const __bf16* __restrict__ W,
    const float* __restrict__ bias,
    __bf16* __restrict__ qb, __bf16* __restrict__ kb, __bf16* __restrict__ vtb) {
  __shared__ __bf16 As[128 * 64];
  __shared__ __bf16 Bs[128 * 64];
  const int bm = blockIdx.y * 128, bn = blockIdx.x * 128;
  const int tid = threadIdx.x;
  const int w = tid >> 6, l = tid & 63;
  const int wr = w >> 1, wc = w & 1;
  const int l15 = l & 15, lg = l >> 4;
  const int srow = w * 32 + (l >> 3);   // + q*8
  const int scol = (l & 7) * 8;
  f32x4 acc[4][4] = {};
  for (int k0 = 0; k0 < K_DIM; k0 += 64) {
#pragma unroll
    for (int q = 0; q < 4; ++q) {
      GLOAD_LDS16(&A[(size_t)(bm + srow + q * 8) * K_DIM + k0 + scol], &As[(w * 32 + q * 8) * 64]);
      GLOAD_LDS16(&W[(size_t)(bn + srow + q * 8) * K_DIM + k0 + scol], &Bs[(w * 32 + q * 8) * 64]);
    }
    __syncthreads();
#pragma unroll
    for (int kk = 0; kk < 2; ++kk) {
      bf16x8 af[4], bfr[4];
#pragma unroll
      for (int i = 0; i < 4; ++i)
        af[i] = *reinterpret_cast<const bf16x8*>(&As[(wr * 64 + i * 16 + l15) * 64 + kk * 32 + lg * 8]);
#pragma unroll
      for (int j = 0; j < 4; ++j)
        bfr[j] = *reinterpret_cast<const bf16x8*>(&Bs[(wc * 64 + j * 16 + l15) * 64 + kk * 32 + lg * 8]);
      __builtin_amdgcn_s_setprio(1);
#pragma unroll
      for (int i = 0; i < 4; ++i)
#pragma unroll
        for (int j = 0; j < 4; ++j)
          acc[i][j] = __builtin_amdgcn_mfma_f32_16x16x32_bf16(af[i], bfr[j], acc[i][j], 0, 0, 0);
      __builtin_amdgcn_s_setprio(0);
    }
    __syncthreads();
  }
#pragma unroll
  for (int i = 0; i < 4; ++i)
#pragma unroll
    for (int j = 0; j < 4; ++j) {
      int n = bn + wc * 64 + j * 16 + l15;
      float bv = bias[n];
      int which = n >> 10, d = n & 1023;
      int h = d >> 6, dk = d & 63;
#pragma unroll
      for (int r = 0; r < 4; ++r) {
        int m = bm + wr * 64 + i * 16 + lg * 4 + r;
        int b = m >> 11, t = m & 2047;
        float v = acc[i][j][r] + bv;
        int bh = b * N_HEADS + h;
        if (which == 0)      qb[((size_t)bh * T_SEQ + t) * D_HEAD + dk] = (__bf16)v;
        else if (which == 1) kb[((size_t)bh * T_SEQ + t) * D_HEAD + dk] = (__bf16)v;
        else                 vtb[((size_t)bh * D_HEAD + dk) * T_SEQ + t] = (__bf16)v;
      }
    }
}

// ---------------- output GEMM (m97 structure) ----------------
__global__ __launch_bounds__(256) void gemm_out(
    const __bf16* __restrict__ A, const __bf16* __restrict__ W,
    const float* __restrict__ bias, float* __restrict__ out) {
  __shared__ __bf16 As[128 * 64];
  __shared__ __bf16 Bs[128 * 64];
  const int bm = blockIdx.y * 128, bn = blockIdx.x * 128;
  const int tid = threadIdx.x;
  const int w = tid >> 6, l = tid & 63;
  const int wr = w >> 1, wc = w & 1;
  const int l15 = l & 15, lg = l >> 4;
  const int srow = w * 32 + (l >> 3);
  const int scol = (l & 7) * 8;
  f32x4 acc[4][4] = {};
  for (int k0 = 0; k0 < K_DIM; k0 += 64) {
#pragma unroll
    for (int q = 0; q < 4; ++q) {
      GLOAD_LDS16(&A[(size_t)(bm + srow + q * 8) * K_DIM + k0 + scol], &As[(w * 32 + q * 8) * 64]);
      GLOAD_LDS16(&W[(size_t)(bn + srow + q * 8) * K_DIM + k0 + scol], &Bs[(w * 32 + q * 8) * 64]);
    }
    __syncthreads();
#pragma unroll
    for (int kk = 0; kk < 2; ++kk) {
      bf16x8 af[4], bfr[4];
#pragma unroll
      for (int i = 0; i < 4; ++i)
        af[i] = *reinterpret_cast<const bf16x8*>(&As[(wr * 64 + i * 16 + l15) * 64 + kk * 32 + lg * 8]);
#pragma unroll
      for (int j = 0; j < 4; ++j)
        bfr[j] = *reinterpret_cast<const bf16x8*>(&Bs[(wc * 64 + j * 16 + l15) * 64 + kk * 32 + lg * 8]);
      __builtin_amdgcn_s_setprio(1);
#pragma unroll
      for (int i = 0; i < 4; ++i)
#pragma unroll
        for (int j = 0; j < 4; ++j)
          acc[i][j] = __builtin_amdgcn_mfma_f32_16x16x32_bf16(af[i], bfr[j], acc[i][j], 0, 0, 0);
      __builtin_amdgcn_s_setprio(0);
    }
    __syncthreads();
  }
#pragma unroll
  for (int i = 0; i < 4; ++i)
#pragma unroll
    for (int j = 0; j < 4; ++j) {
      int n = bn + wc * 64 + j * 16 + l15;
      float bv = bias[n];
#pragma unroll
      for (int r = 0; r < 4; ++r) {
        int m = bm + wr * 64 + i * 16 + lg * 4 + r;
        out[(size_t)m * D_MODEL + n] = acc[i][j][r] + bv;
      }
    }
}

// ---------------- in-place RoPE on q,k (BH,T,DK) ----------------
__global__ __launch_bounds__(256) void rope_qk(__bf16* __restrict__ qb, __bf16* __restrict__ kb,
                                               const float* __restrict__ fc,
                                               const float* __restrict__ fs) {
  int idx = blockIdx.x * 256 + threadIdx.x;  // pair id
  int i = idx & 31;
  int t = (idx >> 5) & (T_SEQ - 1);
  float c = fc[t * 32 + i], s = fs[t * 32 + i];
  bf16x2* qp = reinterpret_cast<bf16x2*>(qb);
  bf16x2* kp = reinterpret_cast<bf16x2*>(kb);
  bf16x2 qv = qp[idx];
  float qre = (float)qv[0], qim = (float)qv[1];
  qv[0] = (__bf16)(qre * c - qim * s);
  qv[1] = (__bf16)(qre * s + qim * c);
  qp[idx] = qv;
  bf16x2 kv = kp[idx];
  float kre = (float)kv[0], kim = (float)kv[1];
  kv[0] = (__bf16)(kre * c - kim * s);
  kv[1] = (__bf16)(kre * s + kim * c);
  kp[idx] = kv;
}

// ---------------- causal flash attention, paired q-tiles ----------------
// 1D grid of 512 blocks; XCD-chunked decode. Block handles q-tiles p and 31-p
// of head bh -> every block does exactly 33 KV-tile visits (load balanced).
// 4 waves; wave w owns q rows [q0+16w, q0+16w+16) of BOTH tiles.
// K/V staged once per KV tile via global_load_lds (linear LDS dest,
// inverse-XOR-swizzled global source), reads XOR-swizzled (conflict-free).
__global__ __launch_bounds__(256) void attn_fwd(
    const __bf16* __restrict__ qb, const __bf16* __restrict__ kb,
    const __bf16* __restrict__ vtb, __bf16* __restrict__ ob) {
  __shared__ __bf16 Ks[64 * 64];      // [key][dk], 16B chunks XOR-permuted by row&7
  __shared__ __bf16 Vs[64 * 64];      // [dk][key], same swizzle
  __shared__ __bf16 Ps[4][16][72];    // per-wave P tile [qrow][key], stride 144B
  const int g = blockIdx.x;
  const int wg = (g & 7) * 64 + (g >> 3);   // same bh stays on one XCD's L2
  const int bh = wg >> 4, p = wg & 15;
  const int q0A = p * 64, q0B = (NT - 1 - p) * 64;
  const int tid = threadIdx.x;
  const int w = tid >> 6, l = tid & 63;
  const int l15 = l & 15, lg = l >> 4;
  const int qbA = q0A + w * 16, qbB = q0B + w * 16;
  const int r8 = l >> 3, c8 = l & 7;
  const int csw = (c8 ^ r8) * 8;   // pre-swizzled global 16B-chunk offset

  bf16x8 aqA[2], aqB[2];
  {
    const __bf16* qp = qb + ((size_t)bh * T_SEQ + qbA + l15) * D_HEAD;
    aqA[0] = *reinterpret_cast<const bf16x8*>(qp + lg * 8);
    aqA[1] = *reinterpret_cast<const bf16x8*>(qp + 32 + lg * 8);
  }
  {
    const __bf16* qp = qb + ((size_t)bh * T_SEQ + qbB + l15) * D_HEAD;
    aqB[0] = *reinterpret_cast<const bf16x8*>(qp + lg * 8);
    aqB[1] = *reinterpret_cast<const bf16x8*>(qp + 32 + lg * 8);
  }
  f32x4 oA[4] = {}, oB[4] = {};
  float mA[4] = {MASKVAL, MASKVAL, MASKVAL, MASKVAL};
  float mB[4] = {MASKVAL, MASKVAL, MASKVAL, MASKVAL};
  float lA[4] = {}, lB[4] = {};

  bf16x8 kf[2][4], vf[2][4];

  auto tile = [&](const bf16x8* aq, f32x4* o, float* m, float* lsum, int qb0, int t0) {
    f32x4 s[4] = {};
    __builtin_amdgcn_s_setprio(1);
#pragma unroll
    for (int kk = 0; kk < 2; ++kk)
#pragma unroll
      for (int cb = 0; cb < 4; ++cb)
        s[cb] = __builtin_amdgcn_mfma_f32_16x16x32_bf16(aq[kk], kf[kk][cb], s[cb], 0, 0, 0);
    __builtin_amdgcn_s_setprio(0);

    float pm[4][4], rmax[4], rsum[4];
    const bool needmask = (t0 + 63 > qb0);  // wave-uniform
    if (needmask) {
#pragma unroll
      for (int r = 0; r < 4; ++r) {
        int qrow = qb0 + lg * 4 + r;
        float mx = MASKVAL;
#pragma unroll
        for (int cb = 0; cb < 4; ++cb) {
          float v = s[cb][r] * SCL_LOG2;
          v = (t0 + cb * 16 + l15 <= qrow) ? v : MASKVAL;
          pm[cb][r] = v;
          mx = fmaxf(mx, v);
        }
        rmax[r] = mx;
      }
    } else {
#pragma unroll
      for (int r = 0; r < 4; ++r) {
        float mx = MASKVAL;
#pragma unroll
        for (int cb = 0; cb < 4; ++cb) {
          float v = s[cb][r] * SCL_LOG2;
          pm[cb][r] = v;
          mx = fmaxf(mx, v);
        }
        rmax[r] = mx;
      }
    }
#pragma unroll
    for (int d = 1; d < 16; d <<= 1)
#pragma unroll
      for (int r = 0; r < 4; ++r)
        rmax[r] = fmaxf(rmax[r], __shfl_xor(rmax[r], d));
    float fac[4];
#pragma unroll
    for (int r = 0; r < 4; ++r) {
      float mnew = fmaxf(m[r], rmax[r]);
      fac[r] = __builtin_amdgcn_exp2f(m[r] - mnew);
      m[r] = mnew;
      float sum = 0.f;
#pragma unroll
      for (int cb = 0; cb < 4; ++cb) {
        float pv = __builtin_amdgcn_exp2f(pm[cb][r] - mnew);
        pm[cb][r] = pv;
        sum += pv;
      }
      rsum[r] = sum;
    }
#pragma unroll
    for (int d = 1; d < 16; d <<= 1)
#pragma unroll
      for (int r = 0; r < 4; ++r)
        rsum[r] += __shfl_xor(rsum[r], d);
#pragma unroll
    for (int r = 0; r < 4; ++r)
      lsum[r] = lsum[r] * fac[r] + rsum[r];
#pragma unroll
    for (int db = 0; db < 4; ++db)
#pragma unroll
      for (int r = 0; r < 4; ++r)
        o[db][r] *= fac[r];
    // P -> LDS (per-wave buffer; same-wave lgkmcnt ordering, no barrier)
#pragma unroll
    for (int cb = 0; cb < 4; ++cb)
#pragma unroll
      for (int r = 0; r < 4; ++r)
        Ps[w][lg * 4 + r][cb * 16 + l15] = (__bf16)pm[cb][r];
    __builtin_amdgcn_s_setprio(1);
#pragma unroll
    for (int kk = 0; kk < 2; ++kk) {
      bf16x8 af = *reinterpret_cast<const bf16x8*>(&Ps[w][l15][kk * 32 + lg * 8]);
#pragma unroll
      for (int db = 0; db < 4; ++db)
        o[db] = __builtin_amdgcn_mfma_f32_16x16x32_bf16(af, vf[kk][db], o[db], 0, 0, 0);
    }
    __builtin_amdgcn_s_setprio(0);
  };

  for (int t0 = 0; t0 <= q0B; t0 += 64) {
    // stage K (rows=key) and V (rows=dk) with inverse-swizzled source
#pragma unroll
    for (int q = 0; q < 2; ++q) {
      int row = w * 16 + q * 8 + r8;
      GLOAD_LDS16(&kb[((size_t)bh * T_SEQ + t0 + row) * D_HEAD + csw], &Ks[(w * 16 + q * 8) * 64]);
      GLOAD_LDS16(&vtb[((size_t)bh * D_HEAD + row) * T_SEQ + t0 + csw], &Vs[(w * 16 + q * 8) * 64]);
    }
    __syncthreads();
    // read K/V fragments once (swizzled reads, conflict-free), reuse for both tiles
#pragma unroll
    for (int kk = 0; kk < 2; ++kk)
#pragma unroll
      for (int cb = 0; cb < 4; ++cb) {
        int row = cb * 16 + l15;
        int col = (kk * 32 + lg * 8) ^ ((row & 7) << 3);
        kf[kk][cb] = *reinterpret_cast<const bf16x8*>(&Ks[row * 64 + col]);
        vf[kk][cb] = *reinterpret_cast<const bf16x8*>(&Vs[row * 64 + col]);
      }
    tile(aqB, oB, mB, lB, qbB, t0);
    if (t0 <= q0A) tile(aqA, oA, mA, lA, qbA, t0);
    __syncthreads();
  }

  const int b = bh >> 4, h = bh & 15;
#pragma unroll
  for (int db = 0; db < 4; ++db)
#pragma unroll
    for (int r = 0; r < 4; ++r) {
      int col = h * 64 + db * 16 + l15;
      int tA = qbA + lg * 4 + r;
      ob[((size_t)b * T_SEQ + tA) * D_MODEL + col] = (__bf16)(oA[db][r] / lA[r]);
      int tB = qbB + lg * 4 + r;
      ob[((size_t)b * T_SEQ + tB) * D_MODEL + col] = (__bf16)(oB[db][r] / lB[r]);
    }
}

extern "C" void kernel_launch(void* const* d_in, const int* in_sizes, int n_in,
                              void* d_out, int out_size, void* d_ws, size_t ws_size,
                              hipStream_t stream) {
  const float* x     = (const float*)d_in[0];
  const float* w_qkv = (const float*)d_in[1];
  const float* b_qkv = (const float*)d_in[2];
  const float* w_out = (const float*)d_in[3];
  const float* b_out = (const float*)d_in[4];
  const float* fc    = (const float*)d_in[5];
  const float* fs    = (const float*)d_in[6];
  float* out = (float*)d_out;
  char* ws = (char*)d_ws;

  __bf16* xb    = (__bf16*)(ws);
  __bf16* wqkvb = (__bf16*)(ws + 8388608);
  __bf16* woutb = (__bf16*)(ws + 14680064);
  __bf16* qbuf  = (__bf16*)(ws + 16777216);
  __bf16* kbuf  = (__bf16*)(ws + 25165824);
  __bf16* vtbuf = (__bf16*)(ws + 33554432);
  __bf16* attnb = xb;  // xb dead after gemm_qkv

  cvt_f32_bf16<<<4096, 256, 0, stream>>>(x, xb, 1048576);
  cvt_f32_bf16<<<3072, 256, 0, stream>>>(w_qkv, wqkvb, 786432);
  cvt_f32_bf16<<<1024, 256, 0, stream>>>(w_out, woutb, 262144);
  gemm_qkv<<<dim3(24, 32), 256, 0, stream>>>(xb, wqkvb, b_qkv, qbuf, kbuf, vtbuf);
  rope_qk<<<8192, 256, 0, stream>>>(qbuf, kbuf, fc, fs);
  attn_fwd<<<512, 256, 0, stream>>>(qbuf, kbuf, vtbuf, attnb);
  gemm_out<<<dim3(8, 32), 256, 0, stream>>>(attnb, woutb, b_out, out);
}

// Round 6
// 162.162 us; speedup vs baseline: 1.1424x; 1.1424x over previous
//
#include <hip/hip_runtime.h>

// ---- problem constants ----
#define T_SEQ 2048
#define D_MODEL 1024
#define N_HEADS 16
#define D_HEAD 64
#define NT 32          // T_SEQ / 64
#define K_DIM 1024

typedef __attribute__((ext_vector_type(8))) __bf16 bf16x8;
typedef __attribute__((ext_vector_type(4))) __bf16 bf16x4;
typedef __attribute__((ext_vector_type(4))) float f32x4;
typedef __attribute__((ext_vector_type(16))) float f32x16;

#define SCL_LOG2 0.180336880f  // 0.125 * log2(e)
#define MASKVAL (-1e30f)

#define GLOAD_LDS16(g, l)                                                     \
  __builtin_amdgcn_global_load_lds(                                           \
      (const __attribute__((address_space(1))) void*)(g),                     \
      (__attribute__((address_space(3))) void*)(l), 16, 0, 0)

// ---------------- f32 -> bf16 convert ----------------
__global__ __launch_bounds__(256) void cvt_f32_bf16(const float* __restrict__ in,
                                                    __bf16* __restrict__ out, int n4) {
  int i = blockIdx.x * 256 + threadIdx.x;
  if (i >= n4) return;
  float4 f = reinterpret_cast<const float4*>(in)[i];
  bf16x4 o;
  o[0] = (__bf16)f.x; o[1] = (__bf16)f.y; o[2] = (__bf16)f.z; o[3] = (__bf16)f.w;
  reinterpret_cast<bf16x4*>(out)[i] = o;
}

// ---------------- QKV GEMM (m97 structure) + fused bias + RoPE, scatter ----------------
__global__ __launch_bounds__(256) void gemm_qkv(
    const __bf16* __restrict__ A, const __bf16* __restrict__ W,
    const float* __restrict__ bias, const float* __restrict__ fc,
    const float* __restrict__ fs,
    __bf16* __restrict__ qb, __bf16* __restrict__ kb, __bf16* __restrict__ vtb) {
  __shared__ __bf16 As[128 * 64];
  __shared__ __bf16 Bs[128 * 64];
  const int bm = blockIdx.y * 128, bn = blockIdx.x * 128;
  const int tid = threadIdx.x;
  const int w = tid >> 6, l = tid & 63;
  const int wr = w >> 1, wc = w & 1;
  const int l15 = l & 15, lg = l >> 4;
  const int srow = w * 32 + (l >> 3);
  const int scol = (l & 7) * 8;
  f32x4 acc[4][4] = {};
  for (int k0 = 0; k0 < K_DIM; k0 += 64) {
#pragma unroll
    for (int q = 0; q < 4; ++q) {
      GLOAD_LDS16(&A[(size_t)(bm + srow + q * 8) * K_DIM + k0 + scol], &As[(w * 32 + q * 8) * 64]);
      GLOAD_LDS16(&W[(size_t)(bn + srow + q * 8) * K_DIM + k0 + scol], &Bs[(w * 32 + q * 8) * 64]);
    }
    __syncthreads();
#pragma unroll
    for (int kk = 0; kk < 2; ++kk) {
      bf16x8 af[4], bfr[4];
#pragma unroll
      for (int i = 0; i < 4; ++i)
        af[i] = *reinterpret_cast<const bf16x8*>(&As[(wr * 64 + i * 16 + l15) * 64 + kk * 32 + lg * 8]);
#pragma unroll
      for (int j = 0; j < 4; ++j)
        bfr[j] = *reinterpret_cast<const bf16x8*>(&Bs[(wc * 64 + j * 16 + l15) * 64 + kk * 32 + lg * 8]);
      __builtin_amdgcn_s_setprio(1);
#pragma unroll
      for (int i = 0; i < 4; ++i)
#pragma unroll
        for (int j = 0; j < 4; ++j)
          acc[i][j] = __builtin_amdgcn_mfma_f32_16x16x32_bf16(af[i], bfr[j], acc[i][j], 0, 0, 0);
      __builtin_amdgcn_s_setprio(0);
    }
    __syncthreads();
  }
#pragma unroll
  for (int i = 0; i < 4; ++i)
#pragma unroll
    for (int j = 0; j < 4; ++j) {
      int n = bn + wc * 64 + j * 16 + l15;
      float bv = bias[n];
      int which = n >> 10, d = n & 1023;
      int h = d >> 6, dk = d & 63;
      int m0 = bm + wr * 64 + i * 16 + lg * 4;
      int b = m0 >> 11;
      int bh = b * N_HEADS + h;
      if (which == 2) {
        bf16x4 pk;
#pragma unroll
        for (int r = 0; r < 4; ++r) pk[r] = (__bf16)(acc[i][j][r] + bv);
        int t0_ = m0 & 2047;
        *reinterpret_cast<bf16x4*>(&vtb[((size_t)bh * D_HEAD + dk) * T_SEQ + t0_]) = pk;
      } else {
        int pi = dk >> 1;
        bool odd = dk & 1;
        __bf16* dst = (which ? kb : qb);
#pragma unroll
        for (int r = 0; r < 4; ++r) {
          int t = (m0 + r) & 2047;
          float v = acc[i][j][r] + bv;
          float part = __shfl_xor(v, 1);
          float c = fc[t * 32 + pi], s = fs[t * 32 + pi];
          float rv = odd ? (part * s + v * c) : (v * c - part * s);
          dst[((size_t)bh * T_SEQ + t) * D_HEAD + dk] = (__bf16)rv;
        }
      }
    }
}

// ---------------- output GEMM (m97 structure) ----------------
__global__ __launch_bounds__(256) void gemm_out(
    const __bf16* __restrict__ A, const __bf16* __restrict__ W,
    const float* __restrict__ bias, float* __restrict__ out) {
  __shared__ __bf16 As[128 * 64];
  __shared__ __bf16 Bs[128 * 64];
  const int bm = blockIdx.y * 128, bn = blockIdx.x * 128;
  const int tid = threadIdx.x;
  const int w = tid >> 6, l = tid & 63;
  const int wr = w >> 1, wc = w & 1;
  const int l15 = l & 15, lg = l >> 4;
  const int srow = w * 32 + (l >> 3);
  const int scol = (l & 7) * 8;
  f32x4 acc[4][4] = {};
  for (int k0 = 0; k0 < K_DIM; k0 += 64) {
#pragma unroll
    for (int q = 0; q < 4; ++q) {
      GLOAD_LDS16(&A[(size_t)(bm + srow + q * 8) * K_DIM + k0 + scol], &As[(w * 32 + q * 8) * 64]);
      GLOAD_LDS16(&W[(size_t)(bn + srow + q * 8) * K_DIM + k0 + scol], &Bs[(w * 32 + q * 8) * 64]);
    }
    __syncthreads();
#pragma unroll
    for (int kk = 0; kk < 2; ++kk) {
      bf16x8 af[4], bfr[4];
#pragma unroll
      for (int i = 0; i < 4; ++i)
        af[i] = *reinterpret_cast<const bf16x8*>(&As[(wr * 64 + i * 16 + l15) * 64 + kk * 32 + lg * 8]);
#pragma unroll
      for (int j = 0; j < 4; ++j)
        bfr[j] = *reinterpret_cast<const bf16x8*>(&Bs[(wc * 64 + j * 16 + l15) * 64 + kk * 32 + lg * 8]);
      __builtin_amdgcn_s_setprio(1);
#pragma unroll
      for (int i = 0; i < 4; ++i)
#pragma unroll
        for (int j = 0; j < 4; ++j)
          acc[i][j] = __builtin_amdgcn_mfma_f32_16x16x32_bf16(af[i], bfr[j], acc[i][j], 0, 0, 0);
      __builtin_amdgcn_s_setprio(0);
    }
    __syncthreads();
  }
#pragma unroll
  for (int i = 0; i < 4; ++i)
#pragma unroll
    for (int j = 0; j < 4; ++j) {
      int n = bn + wc * 64 + j * 16 + l15;
      float bv = bias[n];
#pragma unroll
      for (int r = 0; r < 4; ++r) {
        int m = bm + wr * 64 + i * 16 + lg * 4 + r;
        out[(size_t)m * D_MODEL + n] = acc[i][j][r] + bv;
      }
    }
}

// ---------------- causal flash attention: swapped QK^T, in-register softmax ----------------
// Identical to r5 except the P cross-half exchange is now direction-proof:
// __shfl_xor(.,32) + select instead of v_permlane32_swap (whose vdst/vsrc
// half-direction is unverified on this toolchain).
__global__ __launch_bounds__(256) void attn_fwd(
    const __bf16* __restrict__ qb, const __bf16* __restrict__ kb,
    const __bf16* __restrict__ vtb, __bf16* __restrict__ ob) {
  __shared__ __bf16 Ks[2][64 * 64];   // [key][dk], chunks XOR-swizzled by row&7
  __shared__ __bf16 Vs[2][64 * 64];   // [dk][key], same swizzle
  const int g = blockIdx.x;
  const int xcd = g & 7, s = g >> 3;
  const int bh = xcd * 4 + (s & 3);
  const int praw = s >> 2;
  const int p = (praw < 8) ? praw : 23 - praw;    // complementary CU pairing
  const int q0A = p * 64, q0B = (NT - 1 - p) * 64;
  const int tid = threadIdx.x;
  const int w = tid >> 6, l = tid & 63;
  const int l31 = l & 31, hi = l >> 5;
  const int qrow = (l31 < 16) ? (q0A + w * 16 + l31) : (q0B + w * 16 + l31 - 16);
  const int r8 = l >> 3, c8 = l & 7;
  const int csw = (c8 ^ r8) * 8;                  // inverse-swizzled global chunk

  // Q B-fragments: lane holds col=qrow, k=dk = kc*16 + hi*8 + j
  bf16x8 qf[4];
  {
    const __bf16* qp = qb + ((size_t)bh * T_SEQ + qrow) * D_HEAD + hi * 8;
#pragma unroll
    for (int kc = 0; kc < 4; ++kc)
      qf[kc] = *reinterpret_cast<const bf16x8*>(qp + kc * 16);
  }
  f32x16 o0 = {}, o1 = {};
  float m = MASKVAL, lsum = 0.f;

  auto stage = [&](int buf, int t0) {
    int row = w * 16 + r8;
    GLOAD_LDS16(&kb[((size_t)bh * T_SEQ + t0 + row) * D_HEAD + csw], &Ks[buf][(w * 16) * 64]);
    GLOAD_LDS16(&kb[((size_t)bh * T_SEQ + t0 + row + 8) * D_HEAD + csw], &Ks[buf][(w * 16 + 8) * 64]);
    GLOAD_LDS16(&vtb[((size_t)bh * D_HEAD + row) * T_SEQ + t0 + csw], &Vs[buf][(w * 16) * 64]);
    GLOAD_LDS16(&vtb[((size_t)bh * D_HEAD + row + 8) * T_SEQ + t0 + csw], &Vs[buf][(w * 16 + 8) * 64]);
  };

  stage(0, 0);
  __syncthreads();
  const int nIter = (q0B >> 6) + 1;
  for (int it = 0; it < nIter; ++it) {
    const int t0 = it << 6;
    const int cur = it & 1;
    if (it + 1 < nIter) stage(cur ^ 1, t0 + 64);

    // ---- S^T = K Q^T : A-frag rows = keys, 2 key-blocks of 32 ----
    f32x16 sa0 = {}, sa1 = {};
#pragma unroll
    for (int kc = 0; kc < 4; ++kc) {
      int ch = kc * 2 + hi;
      bf16x8 k0 = *reinterpret_cast<const bf16x8*>(&Ks[cur][l31 * 64 + (ch ^ (l31 & 7)) * 8]);
      bf16x8 k1 = *reinterpret_cast<const bf16x8*>(&Ks[cur][(32 + l31) * 64 + (ch ^ ((32 + l31) & 7)) * 8]);
      __builtin_amdgcn_s_setprio(1);
      sa0 = __builtin_amdgcn_mfma_f32_32x32x16_bf16(k0, qf[kc], sa0, 0, 0, 0);
      sa1 = __builtin_amdgcn_mfma_f32_32x32x16_bf16(k1, qf[kc], sa1, 0, 0, 0);
      __builtin_amdgcn_s_setprio(0);
    }

    // ---- mask + scale: lane-local (key_local = 32a + (r&3)+8*(r>>2)+4*hi) ----
    float sv[32];
    const bool nomask = (t0 + 63 <= q0A + w * 16);
    if (nomask) {
#pragma unroll
      for (int r = 0; r < 16; ++r) { sv[r] = sa0[r] * SCL_LOG2; sv[16 + r] = sa1[r] * SCL_LOG2; }
    } else {
      int thr = qrow - t0 - 4 * hi;
#pragma unroll
      for (int r = 0; r < 16; ++r) {
        int kc0 = (r & 3) + 8 * (r >> 2);
        float v0 = sa0[r] * SCL_LOG2;
        float v1 = sa1[r] * SCL_LOG2;
        sv[r]      = (kc0 <= thr) ? v0 : MASKVAL;
        sv[16 + r] = (kc0 + 32 <= thr) ? v1 : MASKVAL;
      }
    }
    // ---- in-lane max tree + cross-half combine (symmetric -> direction-proof) ----
    float m0 = sv[0], m1 = sv[1], m2 = sv[2], m3 = sv[3];
#pragma unroll
    for (int i = 4; i < 32; i += 4) {
      m0 = fmaxf(m0, sv[i]); m1 = fmaxf(m1, sv[i + 1]);
      m2 = fmaxf(m2, sv[i + 2]); m3 = fmaxf(m3, sv[i + 3]);
    }
    float mx = fmaxf(fmaxf(m0, m1), fmaxf(m2, m3));
    mx = fmaxf(mx, __shfl_xor(mx, 32));
    float mnew = fmaxf(m, mx);
    float fac = __builtin_amdgcn_exp2f(m - mnew);
    m = mnew;
    float s0 = 0.f, s1 = 0.f, s2 = 0.f, s3 = 0.f;
#pragma unroll
    for (int i = 0; i < 32; i += 4) {
      sv[i]     = __builtin_amdgcn_exp2f(sv[i] - mnew);     s0 += sv[i];
      sv[i + 1] = __builtin_amdgcn_exp2f(sv[i + 1] - mnew); s1 += sv[i + 1];
      sv[i + 2] = __builtin_amdgcn_exp2f(sv[i + 2] - mnew); s2 += sv[i + 2];
      sv[i + 3] = __builtin_amdgcn_exp2f(sv[i + 3] - mnew); s3 += sv[i + 3];
    }
    float sum = (s0 + s1) + (s2 + s3);
    sum += __shfl_xor(sum, 32);
    lsum = lsum * fac + sum;
    o0 *= fac;
    o1 *= fac;

    // ---- P -> B-fragments: cvt_pk pairs + direction-proof cross-half exchange ----
    // Lane (l31,hi) holds P at keys 16*kb4 + {0..3,8..11} + 4*hi (pairs c0..c3);
    // it needs the contiguous run 16*kb4 + 8*hi + {0..7}:
    //   hi=0: [c0, c1, partner_c0, partner_c1]
    //   hi=1: [partner_c2, partner_c3, c2, c3]
#pragma unroll
    for (int kb4 = 0; kb4 < 4; ++kb4) {
      unsigned int c0, c1, c2, c3;
      asm("v_cvt_pk_bf16_f32 %0, %1, %2" : "=v"(c0) : "v"(sv[kb4 * 8 + 0]), "v"(sv[kb4 * 8 + 1]));
      asm("v_cvt_pk_bf16_f32 %0, %1, %2" : "=v"(c1) : "v"(sv[kb4 * 8 + 2]), "v"(sv[kb4 * 8 + 3]));
      asm("v_cvt_pk_bf16_f32 %0, %1, %2" : "=v"(c2) : "v"(sv[kb4 * 8 + 4]), "v"(sv[kb4 * 8 + 5]));
      asm("v_cvt_pk_bf16_f32 %0, %1, %2" : "=v"(c3) : "v"(sv[kb4 * 8 + 6]), "v"(sv[kb4 * 8 + 7]));
      unsigned int p0 = (unsigned)__shfl_xor((int)c0, 32);
      unsigned int p1 = (unsigned)__shfl_xor((int)c1, 32);
      unsigned int p2 = (unsigned)__shfl_xor((int)c2, 32);
      unsigned int p3 = (unsigned)__shfl_xor((int)c3, 32);
      union { unsigned int u[4]; bf16x8 v; } cv;
      cv.u[0] = hi ? p2 : c0;
      cv.u[1] = hi ? p3 : c1;
      cv.u[2] = hi ? c2 : p0;
      cv.u[3] = hi ? c3 : p1;
      int ch = kb4 * 2 + hi;
      bf16x8 v0 = *reinterpret_cast<const bf16x8*>(&Vs[cur][l31 * 64 + (ch ^ (l31 & 7)) * 8]);
      bf16x8 v1 = *reinterpret_cast<const bf16x8*>(&Vs[cur][(32 + l31) * 64 + (ch ^ ((32 + l31) & 7)) * 8]);
      __builtin_amdgcn_s_setprio(1);
      o0 = __builtin_amdgcn_mfma_f32_32x32x16_bf16(v0, cv.v, o0, 0, 0, 0);
      o1 = __builtin_amdgcn_mfma_f32_32x32x16_bf16(v1, cv.v, o1, 0, 0, 0);
      __builtin_amdgcn_s_setprio(0);
    }
    __syncthreads();
  }

  // ---- epilogue: O^T[d][q], d = 8*Q + 4*hi + e (o0: d 0-31, o1: d 32-63) ----
  const float inv = 1.0f / lsum;
  const int b = bh >> 4, h = bh & 15;
  __bf16* obase = ob + ((size_t)b * T_SEQ + qrow) * D_MODEL + h * 64;
#pragma unroll
  for (int Q = 0; Q < 4; ++Q) {
    bf16x4 pk0, pk1;
#pragma unroll
    for (int e = 0; e < 4; ++e) {
      pk0[e] = (__bf16)(o0[Q * 4 + e] * inv);
      pk1[e] = (__bf16)(o1[Q * 4 + e] * inv);
    }
    *reinterpret_cast<bf16x4*>(obase + 8 * Q + 4 * hi) = pk0;
    *reinterpret_cast<bf16x4*>(obase + 32 + 8 * Q + 4 * hi) = pk1;
  }
}

extern "C" void kernel_launch(void* const* d_in, const int* in_sizes, int n_in,
                              void* d_out, int out_size, void* d_ws, size_t ws_size,
                              hipStream_t stream) {
  const float* x     = (const float*)d_in[0];
  const float* w_qkv = (const float*)d_in[1];
  const float* b_qkv = (const float*)d_in[2];
  const float* w_out = (const float*)d_in[3];
  const float* b_out = (const float*)d_in[4];
  const float* fc    = (const float*)d_in[5];
  const float* fs    = (const float*)d_in[6];
  float* out = (float*)d_out;
  char* ws = (char*)d_ws;

  __bf16* xb    = (__bf16*)(ws);
  __bf16* wqkvb = (__bf16*)(ws + 8388608);
  __bf16* woutb = (__bf16*)(ws + 14680064);
  __bf16* qbuf  = (__bf16*)(ws + 16777216);
  __bf16* kbuf  = (__bf16*)(ws + 25165824);
  __bf16* vtbuf = (__bf16*)(ws + 33554432);
  __bf16* attnb = xb;  // xb dead after gemm_qkv

  cvt_f32_bf16<<<4096, 256, 0, stream>>>(x, xb, 1048576);
  cvt_f32_bf16<<<3072, 256, 0, stream>>>(w_qkv, wqkvb, 786432);
  cvt_f32_bf16<<<1024, 256, 0, stream>>>(w_out, woutb, 262144);
  gemm_qkv<<<dim3(24, 32), 256, 0, stream>>>(xb, wqkvb, b_qkv, fc, fs, qbuf, kbuf, vtbuf);
  attn_fwd<<<512, 256, 0, stream>>>(qbuf, kbuf, vtbuf, attnb);
  gemm_out<<<dim3(8, 32), 256, 0, stream>>>(attnb, woutb, b_out, out);
}

// Round 7
// 157.641 us; speedup vs baseline: 1.1752x; 1.0287x over previous
//
#include <hip/hip_runtime.h>

// ---- problem constants ----
#define T_SEQ 2048
#define D_MODEL 1024
#define N_HEADS 16
#define D_HEAD 64
#define NT 32          // T_SEQ / 64
#define K_DIM 1024

typedef __attribute__((ext_vector_type(8))) __bf16 bf16x8;
typedef __attribute__((ext_vector_type(4))) __bf16 bf16x4;
typedef __attribute__((ext_vector_type(4))) float f32x4;
typedef __attribute__((ext_vector_type(16))) float f32x16;

#define SCL_LOG2 0.180336880f  // 0.125 * log2(e)
#define MASKVAL (-1e30f)

#define GLOAD_LDS16(g, l)                                                     \
  __builtin_amdgcn_global_load_lds(                                           \
      (const __attribute__((address_space(1))) void*)(g),                     \
      (__attribute__((address_space(3))) void*)(l), 16, 0, 0)

// ---------------- f32 -> bf16 convert ----------------
__global__ __launch_bounds__(256) void cvt_f32_bf16(const float* __restrict__ in,
                                                    __bf16* __restrict__ out, int n4) {
  int i = blockIdx.x * 256 + threadIdx.x;
  if (i >= n4) return;
  float4 f = reinterpret_cast<const float4*>(in)[i];
  bf16x4 o;
  o[0] = (__bf16)f.x; o[1] = (__bf16)f.y; o[2] = (__bf16)f.z; o[3] = (__bf16)f.w;
  reinterpret_cast<bf16x4*>(out)[i] = o;
}

// ---------------- QKV GEMM (m97 structure) + fused bias + RoPE, scatter ----------------
__global__ __launch_bounds__(256) void gemm_qkv(
    const __bf16* __restrict__ A, const __bf16* __restrict__ W,
    const float* __restrict__ bias, const float* __restrict__ fc,
    const float* __restrict__ fs,
    __bf16* __restrict__ qb, __bf16* __restrict__ kb, __bf16* __restrict__ vtb) {
  __shared__ __bf16 As[128 * 64];
  __shared__ __bf16 Bs[128 * 64];
  const int bm = blockIdx.y * 128, bn = blockIdx.x * 128;
  const int tid = threadIdx.x;
  const int w = tid >> 6, l = tid & 63;
  const int wr = w >> 1, wc = w & 1;
  const int l15 = l & 15, lg = l >> 4;
  const int srow = w * 32 + (l >> 3);
  const int scol = (l & 7) * 8;
  f32x4 acc[4][4] = {};
  for (int k0 = 0; k0 < K_DIM; k0 += 64) {
#pragma unroll
    for (int q = 0; q < 4; ++q) {
      GLOAD_LDS16(&A[(size_t)(bm + srow + q * 8) * K_DIM + k0 + scol], &As[(w * 32 + q * 8) * 64]);
      GLOAD_LDS16(&W[(size_t)(bn + srow + q * 8) * K_DIM + k0 + scol], &Bs[(w * 32 + q * 8) * 64]);
    }
    __syncthreads();
#pragma unroll
    for (int kk = 0; kk < 2; ++kk) {
      bf16x8 af[4], bfr[4];
#pragma unroll
      for (int i = 0; i < 4; ++i)
        af[i] = *reinterpret_cast<const bf16x8*>(&As[(wr * 64 + i * 16 + l15) * 64 + kk * 32 + lg * 8]);
#pragma unroll
      for (int j = 0; j < 4; ++j)
        bfr[j] = *reinterpret_cast<const bf16x8*>(&Bs[(wc * 64 + j * 16 + l15) * 64 + kk * 32 + lg * 8]);
      __builtin_amdgcn_s_setprio(1);
#pragma unroll
      for (int i = 0; i < 4; ++i)
#pragma unroll
        for (int j = 0; j < 4; ++j)
          acc[i][j] = __builtin_amdgcn_mfma_f32_16x16x32_bf16(af[i], bfr[j], acc[i][j], 0, 0, 0);
      __builtin_amdgcn_s_setprio(0);
    }
    __syncthreads();
  }
#pragma unroll
  for (int i = 0; i < 4; ++i)
#pragma unroll
    for (int j = 0; j < 4; ++j) {
      int n = bn + wc * 64 + j * 16 + l15;
      float bv = bias[n];
      int which = n >> 10, d = n & 1023;
      int h = d >> 6, dk = d & 63;
      int m0 = bm + wr * 64 + i * 16 + lg * 4;
      int b = m0 >> 11;
      int bh = b * N_HEADS + h;
      if (which == 2) {
        bf16x4 pk;
#pragma unroll
        for (int r = 0; r < 4; ++r) pk[r] = (__bf16)(acc[i][j][r] + bv);
        int t0_ = m0 & 2047;
        *reinterpret_cast<bf16x4*>(&vtb[((size_t)bh * D_HEAD + dk) * T_SEQ + t0_]) = pk;
      } else {
        int pi = dk >> 1;
        bool odd = dk & 1;
        __bf16* dst = (which ? kb : qb);
#pragma unroll
        for (int r = 0; r < 4; ++r) {
          int t = (m0 + r) & 2047;
          float v = acc[i][j][r] + bv;
          float part = __shfl_xor(v, 1);
          float c = fc[t * 32 + pi], s = fs[t * 32 + pi];
          float rv = odd ? (part * s + v * c) : (v * c - part * s);
          dst[((size_t)bh * T_SEQ + t) * D_HEAD + dk] = (__bf16)rv;
        }
      }
    }
}

// ---------------- output GEMM (m97 structure) ----------------
__global__ __launch_bounds__(256) void gemm_out(
    const __bf16* __restrict__ A, const __bf16* __restrict__ W,
    const float* __restrict__ bias, float* __restrict__ out) {
  __shared__ __bf16 As[128 * 64];
  __shared__ __bf16 Bs[128 * 64];
  const int bm = blockIdx.y * 128, bn = blockIdx.x * 128;
  const int tid = threadIdx.x;
  const int w = tid >> 6, l = tid & 63;
  const int wr = w >> 1, wc = w & 1;
  const int l15 = l & 15, lg = l >> 4;
  const int srow = w * 32 + (l >> 3);
  const int scol = (l & 7) * 8;
  f32x4 acc[4][4] = {};
  for (int k0 = 0; k0 < K_DIM; k0 += 64) {
#pragma unroll
    for (int q = 0; q < 4; ++q) {
      GLOAD_LDS16(&A[(size_t)(bm + srow + q * 8) * K_DIM + k0 + scol], &As[(w * 32 + q * 8) * 64]);
      GLOAD_LDS16(&W[(size_t)(bn + srow + q * 8) * K_DIM + k0 + scol], &Bs[(w * 32 + q * 8) * 64]);
    }
    __syncthreads();
#pragma unroll
    for (int kk = 0; kk < 2; ++kk) {
      bf16x8 af[4], bfr[4];
#pragma unroll
      for (int i = 0; i < 4; ++i)
        af[i] = *reinterpret_cast<const bf16x8*>(&As[(wr * 64 + i * 16 + l15) * 64 + kk * 32 + lg * 8]);
#pragma unroll
      for (int j = 0; j < 4; ++j)
        bfr[j] = *reinterpret_cast<const bf16x8*>(&Bs[(wc * 64 + j * 16 + l15) * 64 + kk * 32 + lg * 8]);
      __builtin_amdgcn_s_setprio(1);
#pragma unroll
      for (int i = 0; i < 4; ++i)
#pragma unroll
        for (int j = 0; j < 4; ++j)
          acc[i][j] = __builtin_amdgcn_mfma_f32_16x16x32_bf16(af[i], bfr[j], acc[i][j], 0, 0, 0);
      __builtin_amdgcn_s_setprio(0);
    }
    __syncthreads();
  }
#pragma unroll
  for (int i = 0; i < 4; ++i)
#pragma unroll
    for (int j = 0; j < 4; ++j) {
      int n = bn + wc * 64 + j * 16 + l15;
      float bv = bias[n];
#pragma unroll
      for (int r = 0; r < 4; ++r) {
        int m = bm + wr * 64 + i * 16 + lg * 4 + r;
        out[(size_t)m * D_MODEL + n] = acc[i][j][r] + bv;
      }
    }
}

// ---------------- causal flash attention: LDS-free, barrier-free ----------------
// 512 blocks x 128 threads (2 waves). Each WAVE independently handles strip pair
// (stA=k, stB=63-k) of one bh: 32 q-rows each, tile counts vA+vB = 33 (balanced).
// K/V tiles read straight from global (L2-resident: 512KB/head, 4 heads/XCD) into
// registers; K double-buffered one tile ahead; both strips share each tile.
// Swapped QK^T (32x32x16, A=K, B=Q^T): lane owns one q-col -> softmax lane-local.
__global__ __launch_bounds__(128) void attn_fwd(
    const __bf16* __restrict__ qb, const __bf16* __restrict__ kb,
    const __bf16* __restrict__ vtb, __bf16* __restrict__ ob) {
  const int g = blockIdx.x;
  const int xcd = g & 7, s = g >> 3;              // s in [0,64)
  const int bh = xcd * 4 + (s & 3);               // 4 heads per XCD for L2 locality
  const int w = threadIdx.x >> 6, l = threadIdx.x & 63;
  const int k = (s >> 2) * 2 + w;                 // pair id in [0,32)
  const int stA = k, stB = 63 - k;
  const int vA = (stA >> 1) + 1, vB = (stB >> 1) + 1;   // KV tiles per strip
  const int sbA = stA * 32, sbB = stB * 32;
  const int l31 = l & 31, hi = l >> 5;
  const int qrowA = sbA + l31, qrowB = sbB + l31;

  // Q B-fragments: lane holds col=qrow, k=dk = kc*16 + hi*8 + j
  bf16x8 qfA[4], qfB[4];
  {
    const __bf16* qp = qb + ((size_t)bh * T_SEQ + qrowA) * D_HEAD + hi * 8;
#pragma unroll
    for (int kc = 0; kc < 4; ++kc) qfA[kc] = *reinterpret_cast<const bf16x8*>(qp + kc * 16);
  }
  {
    const __bf16* qp = qb + ((size_t)bh * T_SEQ + qrowB) * D_HEAD + hi * 8;
#pragma unroll
    for (int kc = 0; kc < 4; ++kc) qfB[kc] = *reinterpret_cast<const bf16x8*>(qp + kc * 16);
  }
  f32x16 oA0 = {}, oA1 = {}, oB0 = {}, oB1 = {};
  float mA = MASKVAL, lA = 0.f, mB = MASKVAL, lB = 0.f;

  const __bf16* kbase = kb + ((size_t)bh * T_SEQ + l31) * D_HEAD + hi * 8;
  const __bf16* vbase = vtb + ((size_t)bh * D_HEAD + l31) * T_SEQ + hi * 8;

  // kf[a*4+kc] = K[t0 + a*32 + l31][kc*16 + hi*8 + 0..7]
  auto loadK = [&](bf16x8* dst, int t0) {
#pragma unroll
    for (int a = 0; a < 2; ++a)
#pragma unroll
      for (int kc = 0; kc < 4; ++kc)
        dst[a * 4 + kc] = *reinterpret_cast<const bf16x8*>(kbase + ((size_t)(t0 + a * 32)) * D_HEAD + kc * 16);
  };
  // vf[a*4+ks] = V^T[a*32 + l31][t0 + ks*16 + hi*8 + 0..7]
  auto loadV = [&](bf16x8* dst, int t0) {
#pragma unroll
    for (int a = 0; a < 2; ++a)
#pragma unroll
      for (int ks = 0; ks < 4; ++ks)
        dst[a * 4 + ks] = *reinterpret_cast<const bf16x8*>(vbase + (size_t)a * 32 * T_SEQ + t0 + ks * 16);
  };

  auto process = [&](const bf16x8* kf, const bf16x8* vf, const bf16x8* qf,
                     f32x16& o0, f32x16& o1, float& m, float& lsum,
                     int sb, int t0) {
    // ---- S^T = K Q^T ----
    f32x16 sa0 = {}, sa1 = {};
    __builtin_amdgcn_s_setprio(1);
#pragma unroll
    for (int kc = 0; kc < 4; ++kc) {
      sa0 = __builtin_amdgcn_mfma_f32_32x32x16_bf16(kf[kc], qf[kc], sa0, 0, 0, 0);
      sa1 = __builtin_amdgcn_mfma_f32_32x32x16_bf16(kf[4 + kc], qf[kc], sa1, 0, 0, 0);
    }
    __builtin_amdgcn_s_setprio(0);

    // ---- mask in raw domain (key_local = 32a + (r&3)+8*(r>>2)+4*hi) ----
    float sv[32];
    if (t0 + 63 <= sb) {
#pragma unroll
      for (int r = 0; r < 16; ++r) { sv[r] = sa0[r]; sv[16 + r] = sa1[r]; }
    } else {
      int thr = sb + l31 - t0 - 4 * hi;
#pragma unroll
      for (int r = 0; r < 16; ++r) {
        int kc0 = (r & 3) + 8 * (r >> 2);
        sv[r]      = (kc0 <= thr) ? sa0[r] : MASKVAL;
        sv[16 + r] = (kc0 + 32 <= thr) ? sa1[r] : MASKVAL;
      }
    }
    // ---- max (raw), 4 parallel trees + cross-half ----
    float m0 = sv[0], m1 = sv[1], m2 = sv[2], m3 = sv[3];
#pragma unroll
    for (int i = 4; i < 32; i += 4) {
      m0 = fmaxf(m0, sv[i]); m1 = fmaxf(m1, sv[i + 1]);
      m2 = fmaxf(m2, sv[i + 2]); m3 = fmaxf(m3, sv[i + 3]);
    }
    float mx = fmaxf(fmaxf(m0, m1), fmaxf(m2, m3));
    mx = fmaxf(mx, __shfl_xor(mx, 32));
    float mnew = fmaxf(m, mx * SCL_LOG2);
    float fac = __builtin_amdgcn_exp2f(m - mnew);
    m = mnew;
    // ---- p = exp2(fma(s, SCL, -mnew)), sum ----
    float s0 = 0.f, s1 = 0.f, s2 = 0.f, s3 = 0.f;
#pragma unroll
    for (int i = 0; i < 32; i += 4) {
      sv[i]     = __builtin_amdgcn_exp2f(__builtin_fmaf(sv[i],     SCL_LOG2, -mnew)); s0 += sv[i];
      sv[i + 1] = __builtin_amdgcn_exp2f(__builtin_fmaf(sv[i + 1], SCL_LOG2, -mnew)); s1 += sv[i + 1];
      sv[i + 2] = __builtin_amdgcn_exp2f(__builtin_fmaf(sv[i + 2], SCL_LOG2, -mnew)); s2 += sv[i + 2];
      sv[i + 3] = __builtin_amdgcn_exp2f(__builtin_fmaf(sv[i + 3], SCL_LOG2, -mnew)); s3 += sv[i + 3];
    }
    float sum = (s0 + s1) + (s2 + s3);
    sum += __shfl_xor(sum, 32);
    lsum = lsum * fac + sum;
    o0 *= fac;
    o1 *= fac;

    // ---- P -> B-fragments (cvt_pk + direction-proof cross-half exchange), PV ----
#pragma unroll
    for (int kb4 = 0; kb4 < 4; ++kb4) {
      unsigned int c0, c1, c2, c3;
      asm("v_cvt_pk_bf16_f32 %0, %1, %2" : "=v"(c0) : "v"(sv[kb4 * 8 + 0]), "v"(sv[kb4 * 8 + 1]));
      asm("v_cvt_pk_bf16_f32 %0, %1, %2" : "=v"(c1) : "v"(sv[kb4 * 8 + 2]), "v"(sv[kb4 * 8 + 3]));
      asm("v_cvt_pk_bf16_f32 %0, %1, %2" : "=v"(c2) : "v"(sv[kb4 * 8 + 4]), "v"(sv[kb4 * 8 + 5]));
      asm("v_cvt_pk_bf16_f32 %0, %1, %2" : "=v"(c3) : "v"(sv[kb4 * 8 + 6]), "v"(sv[kb4 * 8 + 7]));
      unsigned int p0 = (unsigned)__shfl_xor((int)c0, 32);
      unsigned int p1 = (unsigned)__shfl_xor((int)c1, 32);
      unsigned int p2 = (unsigned)__shfl_xor((int)c2, 32);
      unsigned int p3 = (unsigned)__shfl_xor((int)c3, 32);
      union { unsigned int u[4]; bf16x8 v; } cv;
      cv.u[0] = hi ? p2 : c0;
      cv.u[1] = hi ? p3 : c1;
      cv.u[2] = hi ? c2 : p0;
      cv.u[3] = hi ? c3 : p1;
      __builtin_amdgcn_s_setprio(1);
      o0 = __builtin_amdgcn_mfma_f32_32x32x16_bf16(vf[kb4], cv.v, o0, 0, 0, 0);
      o1 = __builtin_amdgcn_mfma_f32_32x32x16_bf16(vf[4 + kb4], cv.v, o1, 0, 0, 0);
      __builtin_amdgcn_s_setprio(0);
    }
  };

  // ---- main loop: K ping-pong (static buffers), V per-iter, no barriers ----
  bf16x8 kf0[8], kf1[8], vf[8];
  loadK(kf0, 0);
  int it = 0;
  while (true) {
    int t0 = it * 64;
    loadV(vf, t0);
    if (it + 1 < vB) loadK(kf1, t0 + 64);
    process(kf0, vf, qfB, oB0, oB1, mB, lB, sbB, t0);
    if (it < vA) process(kf0, vf, qfA, oA0, oA1, mA, lA, sbA, t0);
    ++it;
    if (it >= vB) break;
    t0 = it * 64;
    loadV(vf, t0);
    if (it + 1 < vB) loadK(kf0, t0 + 64);
    process(kf1, vf, qfB, oB0, oB1, mB, lB, sbB, t0);
    if (it < vA) process(kf1, vf, qfA, oA0, oA1, mA, lA, sbA, t0);
    ++it;
    if (it >= vB) break;
  }

  // ---- epilogue: O^T[d][q], d = 8*Q + 4*hi + e (o0: d 0-31, o1: +32) ----
  const int b = bh >> 4, h = bh & 15;
  auto epi = [&](const f32x16& o0, const f32x16& o1, float lsum, int qrow) {
    const float inv = 1.0f / lsum;
    __bf16* obase = ob + ((size_t)b * T_SEQ + qrow) * D_MODEL + h * 64;
#pragma unroll
    for (int Q = 0; Q < 4; ++Q) {
      bf16x4 pk0, pk1;
#pragma unroll
      for (int e = 0; e < 4; ++e) {
        pk0[e] = (__bf16)(o0[Q * 4 + e] * inv);
        pk1[e] = (__bf16)(o1[Q * 4 + e] * inv);
      }
      *reinterpret_cast<bf16x4*>(obase + 8 * Q + 4 * hi) = pk0;
      *reinterpret_cast<bf16x4*>(obase + 32 + 8 * Q + 4 * hi) = pk1;
    }
  };
  epi(oA0, oA1, lA, qrowA);
  epi(oB0, oB1, lB, qrowB);
}

extern "C" void kernel_launch(void* const* d_in, const int* in_sizes, int n_in,
                              void* d_out, int out_size, void* d_ws, size_t ws_size,
                              hipStream_t stream) {
  const float* x     = (const float*)d_in[0];
  const float* w_qkv = (const float*)d_in[1];
  const float* b_qkv = (const float*)d_in[2];
  const float* w_out = (const float*)d_in[3];
  const float* b_out = (const float*)d_in[4];
  const float* fc    = (const float*)d_in[5];
  const float* fs    = (const float*)d_in[6];
  float* out = (float*)d_out;
  char* ws = (char*)d_ws;

  __bf16* xb    = (__bf16*)(ws);
  __bf16* wqkvb = (__bf16*)(ws + 8388608);
  __bf16* woutb = (__bf16*)(ws + 14680064);
  __bf16* qbuf  = (__bf16*)(ws + 16777216);
  __bf16* kbuf  = (__bf16*)(ws + 25165824);
  __bf16* vtbuf = (__bf16*)(ws + 33554432);
  __bf16* attnb = xb;  // xb dead after gemm_qkv

  cvt_f32_bf16<<<4096, 256, 0, stream>>>(x, xb, 1048576);
  cvt_f32_bf16<<<3072, 256, 0, stream>>>(w_qkv, wqkvb, 786432);
  cvt_f32_bf16<<<1024, 256, 0, stream>>>(w_out, woutb, 262144);
  gemm_qkv<<<dim3(24, 32), 256, 0, stream>>>(xb, wqkvb, b_qkv, fc, fs, qbuf, kbuf, vtbuf);
  attn_fwd<<<512, 128, 0, stream>>>(qbuf, kbuf, vtbuf, attnb);
  gemm_out<<<dim3(8, 32), 256, 0, stream>>>(attnb, woutb, b_out, out);
}

// Round 8
// 151.468 us; speedup vs baseline: 1.2231x; 1.0408x over previous
//
#include <hip/hip_runtime.h>

// ---- problem constants ----
#define T_SEQ 2048
#define D_MODEL 1024
#define N_HEADS 16
#define D_HEAD 64
#define NT 32          // T_SEQ / 64
#define K_DIM 1024

typedef __attribute__((ext_vector_type(8))) __bf16 bf16x8;
typedef __attribute__((ext_vector_type(4))) __bf16 bf16x4;
typedef __attribute__((ext_vector_type(4))) float f32x4;
typedef __attribute__((ext_vector_type(16))) float f32x16;

#define SCL_LOG2 0.180336880f  // 0.125 * log2(e)
#define MASKVAL (-1e30f)

#define GLOAD_LDS16(g, l)                                                     \
  __builtin_amdgcn_global_load_lds(                                           \
      (const __attribute__((address_space(1))) void*)(g),                     \
      (__attribute__((address_space(3))) void*)(l), 16, 0, 0)

// ---------------- fused f32 -> bf16 convert (x | w_qkv | w_out in one launch) ----------------
#define N4_X 1048576
#define N4_WQ 786432
#define N4_WO 262144
__global__ __launch_bounds__(256) void cvt_all(
    const float* __restrict__ x, const float* __restrict__ wq, const float* __restrict__ wo,
    __bf16* __restrict__ xb, __bf16* __restrict__ wqb, __bf16* __restrict__ wob) {
  int i = blockIdx.x * 256 + threadIdx.x;
  const float* src;
  __bf16* dst;
  int off;
  if (i < N4_X)             { src = x;  dst = xb;  off = i; }
  else if (i < N4_X + N4_WQ){ src = wq; dst = wqb; off = i - N4_X; }
  else                      { src = wo; dst = wob; off = i - (N4_X + N4_WQ); }
  float4 f = reinterpret_cast<const float4*>(src)[off];
  bf16x4 o;
  o[0] = (__bf16)f.x; o[1] = (__bf16)f.y; o[2] = (__bf16)f.z; o[3] = (__bf16)f.w;
  reinterpret_cast<bf16x4*>(dst)[off] = o;
}

// ---------------- QKV GEMM (m97 structure) + fused bias + RoPE, scatter ----------------
__global__ __launch_bounds__(256) void gemm_qkv(
    const __bf16* __restrict__ A, const __bf16* __restrict__ W,
    const float* __restrict__ bias, const float* __restrict__ fc,
    const float* __restrict__ fs,
    __bf16* __restrict__ qb, __bf16* __restrict__ kb, __bf16* __restrict__ vtb) {
  __shared__ __bf16 As[128 * 64];
  __shared__ __bf16 Bs[128 * 64];
  const int bm = blockIdx.y * 128, bn = blockIdx.x * 128;
  const int tid = threadIdx.x;
  const int w = tid >> 6, l = tid & 63;
  const int wr = w >> 1, wc = w & 1;
  const int l15 = l & 15, lg = l >> 4;
  const int srow = w * 32 + (l >> 3);
  const int scol = (l & 7) * 8;
  f32x4 acc[4][4] = {};
  for (int k0 = 0; k0 < K_DIM; k0 += 64) {
#pragma unroll
    for (int q = 0; q < 4; ++q) {
      GLOAD_LDS16(&A[(size_t)(bm + srow + q * 8) * K_DIM + k0 + scol], &As[(w * 32 + q * 8) * 64]);
      GLOAD_LDS16(&W[(size_t)(bn + srow + q * 8) * K_DIM + k0 + scol], &Bs[(w * 32 + q * 8) * 64]);
    }
    __syncthreads();
#pragma unroll
    for (int kk = 0; kk < 2; ++kk) {
      bf16x8 af[4], bfr[4];
#pragma unroll
      for (int i = 0; i < 4; ++i)
        af[i] = *reinterpret_cast<const bf16x8*>(&As[(wr * 64 + i * 16 + l15) * 64 + kk * 32 + lg * 8]);
#pragma unroll
      for (int j = 0; j < 4; ++j)
        bfr[j] = *reinterpret_cast<const bf16x8*>(&Bs[(wc * 64 + j * 16 + l15) * 64 + kk * 32 + lg * 8]);
      __builtin_amdgcn_s_setprio(1);
#pragma unroll
      for (int i = 0; i < 4; ++i)
#pragma unroll
        for (int j = 0; j < 4; ++j)
          acc[i][j] = __builtin_amdgcn_mfma_f32_16x16x32_bf16(af[i], bfr[j], acc[i][j], 0, 0, 0);
      __builtin_amdgcn_s_setprio(0);
    }
    __syncthreads();
  }
#pragma unroll
  for (int i = 0; i < 4; ++i)
#pragma unroll
    for (int j = 0; j < 4; ++j) {
      int n = bn + wc * 64 + j * 16 + l15;
      float bv = bias[n];
      int which = n >> 10, d = n & 1023;
      int h = d >> 6, dk = d & 63;
      int m0 = bm + wr * 64 + i * 16 + lg * 4;
      int b = m0 >> 11;
      int bh = b * N_HEADS + h;
      if (which == 2) {
        bf16x4 pk;
#pragma unroll
        for (int r = 0; r < 4; ++r) pk[r] = (__bf16)(acc[i][j][r] + bv);
        int t0_ = m0 & 2047;
        *reinterpret_cast<bf16x4*>(&vtb[((size_t)bh * D_HEAD + dk) * T_SEQ + t0_]) = pk;
      } else {
        int pi = dk >> 1;
        bool odd = dk & 1;
        __bf16* dst = (which ? kb : qb);
#pragma unroll
        for (int r = 0; r < 4; ++r) {
          int t = (m0 + r) & 2047;
          float v = acc[i][j][r] + bv;
          float part = __shfl_xor(v, 1);
          float c = fc[t * 32 + pi], s = fs[t * 32 + pi];
          float rv = odd ? (part * s + v * c) : (v * c - part * s);
          dst[((size_t)bh * T_SEQ + t) * D_HEAD + dk] = (__bf16)rv;
        }
      }
    }
}

// ---------------- output GEMM (m97 structure) ----------------
__global__ __launch_bounds__(256) void gemm_out(
    const __bf16* __restrict__ A, const __bf16* __restrict__ W,
    const float* __restrict__ bias, float* __restrict__ out) {
  __shared__ __bf16 As[128 * 64];
  __shared__ __bf16 Bs[128 * 64];
  const int bm = blockIdx.y * 128, bn = blockIdx.x * 128;
  const int tid = threadIdx.x;
  const int w = tid >> 6, l = tid & 63;
  const int wr = w >> 1, wc = w & 1;
  const int l15 = l & 15, lg = l >> 4;
  const int srow = w * 32 + (l >> 3);
  const int scol = (l & 7) * 8;
  f32x4 acc[4][4] = {};
  for (int k0 = 0; k0 < K_DIM; k0 += 64) {
#pragma unroll
    for (int q = 0; q < 4; ++q) {
      GLOAD_LDS16(&A[(size_t)(bm + srow + q * 8) * K_DIM + k0 + scol], &As[(w * 32 + q * 8) * 64]);
      GLOAD_LDS16(&W[(size_t)(bn + srow + q * 8) * K_DIM + k0 + scol], &Bs[(w * 32 + q * 8) * 64]);
    }
    __syncthreads();
#pragma unroll
    for (int kk = 0; kk < 2; ++kk) {
      bf16x8 af[4], bfr[4];
#pragma unroll
      for (int i = 0; i < 4; ++i)
        af[i] = *reinterpret_cast<const bf16x8*>(&As[(wr * 64 + i * 16 + l15) * 64 + kk * 32 + lg * 8]);
#pragma unroll
      for (int j = 0; j < 4; ++j)
        bfr[j] = *reinterpret_cast<const bf16x8*>(&Bs[(wc * 64 + j * 16 + l15) * 64 + kk * 32 + lg * 8]);
      __builtin_amdgcn_s_setprio(1);
#pragma unroll
      for (int i = 0; i < 4; ++i)
#pragma unroll
        for (int j = 0; j < 4; ++j)
          acc[i][j] = __builtin_amdgcn_mfma_f32_16x16x32_bf16(af[i], bfr[j], acc[i][j], 0, 0, 0);
      __builtin_amdgcn_s_setprio(0);
    }
    __syncthreads();
  }
#pragma unroll
  for (int i = 0; i < 4; ++i)
#pragma unroll
    for (int j = 0; j < 4; ++j) {
      int n = bn + wc * 64 + j * 16 + l15;
      float bv = bias[n];
#pragma unroll
      for (int r = 0; r < 4; ++r) {
        int m = bm + wr * 64 + i * 16 + lg * 4 + r;
        out[(size_t)m * D_MODEL + n] = acc[i][j][r] + bv;
      }
    }
}

// ---------------- causal flash attention: LDS-free loop + split-K x2 ----------------
// 1024 blocks x 128 threads (2 waves). Block owns strip pair (stA=k, stB=63-k) of one
// bh; wave w processes KV tiles it = w, w+2, ... with private (m,l,o) -> 8 waves/CU
// (2/SIMD) for latency hiding. Partials merged exactly via LDS at the end (1 barrier).
// K/V read straight from global (L2-resident) into registers; K prefetched 2 tiles ahead.
__global__ __launch_bounds__(128) void attn_fwd(
    const __bf16* __restrict__ qb, const __bf16* __restrict__ kb,
    const __bf16* __restrict__ vtb, __bf16* __restrict__ ob) {
  __shared__ float osm[4][64][16];   // wave1 partial O, 16B chunks XOR'd by lane&3
  __shared__ float mlm[4][64];       // wave1 {mA,lA,mB,lB}
  const int g = blockIdx.x;
  const int xcd = g & 7, s = g >> 3;              // s in [0,128)
  const int bh = xcd * 4 + (s & 3);               // 4 heads per XCD for L2 locality
  const int k = s >> 2;                           // pair id in [0,32)
  const int w = threadIdx.x >> 6, l = threadIdx.x & 63;
  const int stA = k, stB = 63 - k;
  const int vA = (stA >> 1) + 1, vB = (stB >> 1) + 1;   // KV tiles per strip
  const int sbA = stA * 32, sbB = stB * 32;
  const int l31 = l & 31, hi = l >> 5;
  const int qrowA = sbA + l31, qrowB = sbB + l31;

  // Q B-fragments: lane holds col=qrow, k=dk = kc*16 + hi*8 + j
  bf16x8 qfA[4], qfB[4];
  {
    const __bf16* qp = qb + ((size_t)bh * T_SEQ + qrowA) * D_HEAD + hi * 8;
#pragma unroll
    for (int kc = 0; kc < 4; ++kc) qfA[kc] = *reinterpret_cast<const bf16x8*>(qp + kc * 16);
  }
  {
    const __bf16* qp = qb + ((size_t)bh * T_SEQ + qrowB) * D_HEAD + hi * 8;
#pragma unroll
    for (int kc = 0; kc < 4; ++kc) qfB[kc] = *reinterpret_cast<const bf16x8*>(qp + kc * 16);
  }
  f32x16 oA0 = {}, oA1 = {}, oB0 = {}, oB1 = {};
  float mA = MASKVAL, lA = 0.f, mB = MASKVAL, lB = 0.f;

  const __bf16* kbase = kb + ((size_t)bh * T_SEQ + l31) * D_HEAD + hi * 8;
  const __bf16* vbase = vtb + ((size_t)bh * D_HEAD + l31) * T_SEQ + hi * 8;

  auto loadK = [&](bf16x8* dst, int t0) {
#pragma unroll
    for (int a = 0; a < 2; ++a)
#pragma unroll
      for (int kc = 0; kc < 4; ++kc)
        dst[a * 4 + kc] = *reinterpret_cast<const bf16x8*>(kbase + ((size_t)(t0 + a * 32)) * D_HEAD + kc * 16);
  };
  auto loadV = [&](bf16x8* dst, int t0) {
#pragma unroll
    for (int a = 0; a < 2; ++a)
#pragma unroll
      for (int ks = 0; ks < 4; ++ks)
        dst[a * 4 + ks] = *reinterpret_cast<const bf16x8*>(vbase + (size_t)a * 32 * T_SEQ + t0 + ks * 16);
  };

  auto process = [&](const bf16x8* kf, const bf16x8* vf, const bf16x8* qf,
                     f32x16& o0, f32x16& o1, float& m, float& lsum,
                     int sb, int t0) {
    f32x16 sa0 = {}, sa1 = {};
    __builtin_amdgcn_s_setprio(1);
#pragma unroll
    for (int kc = 0; kc < 4; ++kc) {
      sa0 = __builtin_amdgcn_mfma_f32_32x32x16_bf16(kf[kc], qf[kc], sa0, 0, 0, 0);
      sa1 = __builtin_amdgcn_mfma_f32_32x32x16_bf16(kf[4 + kc], qf[kc], sa1, 0, 0, 0);
    }
    __builtin_amdgcn_s_setprio(0);

    float sv[32];
    if (t0 + 63 <= sb) {
#pragma unroll
      for (int r = 0; r < 16; ++r) { sv[r] = sa0[r]; sv[16 + r] = sa1[r]; }
    } else {
      int thr = sb + l31 - t0 - 4 * hi;
#pragma unroll
      for (int r = 0; r < 16; ++r) {
        int kc0 = (r & 3) + 8 * (r >> 2);
        sv[r]      = (kc0 <= thr) ? sa0[r] : MASKVAL;
        sv[16 + r] = (kc0 + 32 <= thr) ? sa1[r] : MASKVAL;
      }
    }
    float m0 = sv[0], m1 = sv[1], m2 = sv[2], m3 = sv[3];
#pragma unroll
    for (int i = 4; i < 32; i += 4) {
      m0 = fmaxf(m0, sv[i]); m1 = fmaxf(m1, sv[i + 1]);
      m2 = fmaxf(m2, sv[i + 2]); m3 = fmaxf(m3, sv[i + 3]);
    }
    float mx = fmaxf(fmaxf(m0, m1), fmaxf(m2, m3));
    mx = fmaxf(mx, __shfl_xor(mx, 32));
    float mnew = fmaxf(m, mx * SCL_LOG2);
    float fac = __builtin_amdgcn_exp2f(m - mnew);
    m = mnew;
    float s0 = 0.f, s1 = 0.f, s2 = 0.f, s3 = 0.f;
#pragma unroll
    for (int i = 0; i < 32; i += 4) {
      sv[i]     = __builtin_amdgcn_exp2f(__builtin_fmaf(sv[i],     SCL_LOG2, -mnew)); s0 += sv[i];
      sv[i + 1] = __builtin_amdgcn_exp2f(__builtin_fmaf(sv[i + 1], SCL_LOG2, -mnew)); s1 += sv[i + 1];
      sv[i + 2] = __builtin_amdgcn_exp2f(__builtin_fmaf(sv[i + 2], SCL_LOG2, -mnew)); s2 += sv[i + 2];
      sv[i + 3] = __builtin_amdgcn_exp2f(__builtin_fmaf(sv[i + 3], SCL_LOG2, -mnew)); s3 += sv[i + 3];
    }
    float sum = (s0 + s1) + (s2 + s3);
    sum += __shfl_xor(sum, 32);
    lsum = lsum * fac + sum;
    o0 *= fac;
    o1 *= fac;

#pragma unroll
    for (int kb4 = 0; kb4 < 4; ++kb4) {
      unsigned int c0, c1, c2, c3;
      asm("v_cvt_pk_bf16_f32 %0, %1, %2" : "=v"(c0) : "v"(sv[kb4 * 8 + 0]), "v"(sv[kb4 * 8 + 1]));
      asm("v_cvt_pk_bf16_f32 %0, %1, %2" : "=v"(c1) : "v"(sv[kb4 * 8 + 2]), "v"(sv[kb4 * 8 + 3]));
      asm("v_cvt_pk_bf16_f32 %0, %1, %2" : "=v"(c2) : "v"(sv[kb4 * 8 + 4]), "v"(sv[kb4 * 8 + 5]));
      asm("v_cvt_pk_bf16_f32 %0, %1, %2" : "=v"(c3) : "v"(sv[kb4 * 8 + 6]), "v"(sv[kb4 * 8 + 7]));
      unsigned int p0 = (unsigned)__shfl_xor((int)c0, 32);
      unsigned int p1 = (unsigned)__shfl_xor((int)c1, 32);
      unsigned int p2 = (unsigned)__shfl_xor((int)c2, 32);
      unsigned int p3 = (unsigned)__shfl_xor((int)c3, 32);
      union { unsigned int u[4]; bf16x8 v; } cv;
      cv.u[0] = hi ? p2 : c0;
      cv.u[1] = hi ? p3 : c1;
      cv.u[2] = hi ? c2 : p0;
      cv.u[3] = hi ? c3 : p1;
      __builtin_amdgcn_s_setprio(1);
      o0 = __builtin_amdgcn_mfma_f32_32x32x16_bf16(vf[kb4], cv.v, o0, 0, 0, 0);
      o1 = __builtin_amdgcn_mfma_f32_32x32x16_bf16(vf[4 + kb4], cv.v, o1, 0, 0, 0);
      __builtin_amdgcn_s_setprio(0);
    }
  };

  // ---- main loop: this wave's tiles it = w, w+2, ...; K ping-pong 2 ahead ----
  bf16x8 kf0[8], kf1[8], vf[8];
  loadK(kf0, w * 64);
  int it = w;
  while (true) {
    int t0 = it * 64;
    loadV(vf, t0);
    if (it + 2 < vB) loadK(kf1, t0 + 128);
    process(kf0, vf, qfB, oB0, oB1, mB, lB, sbB, t0);
    if (it < vA) process(kf0, vf, qfA, oA0, oA1, mA, lA, sbA, t0);
    it += 2;
    if (it >= vB) break;
    t0 = it * 64;
    loadV(vf, t0);
    if (it + 2 < vB) loadK(kf0, t0 + 128);
    process(kf1, vf, qfB, oB0, oB1, mB, lB, sbB, t0);
    if (it < vA) process(kf1, vf, qfA, oA0, oA1, mA, lA, sbA, t0);
    it += 2;
    if (it >= vB) break;
  }

  // ---- split-K merge: wave1 publishes, wave0 merges exactly and writes ----
  auto publish = [&](int buf, const f32x16& o) {
#pragma unroll
    for (int c = 0; c < 4; ++c) {
      f32x4 ch;
      ch[0] = o[c * 4 + 0]; ch[1] = o[c * 4 + 1];
      ch[2] = o[c * 4 + 2]; ch[3] = o[c * 4 + 3];
      *reinterpret_cast<f32x4*>(&osm[buf][l][(c ^ (l & 3)) * 4]) = ch;
    }
  };
  auto absorb = [&](int buf, f32x16& o, float f0, float f1) {
#pragma unroll
    for (int c = 0; c < 4; ++c) {
      f32x4 ch = *reinterpret_cast<const f32x4*>(&osm[buf][l][(c ^ (l & 3)) * 4]);
#pragma unroll
      for (int e = 0; e < 4; ++e) o[c * 4 + e] = o[c * 4 + e] * f0 + ch[e] * f1;
    }
  };
  if (w == 1) {
    publish(0, oA0); publish(1, oA1); publish(2, oB0); publish(3, oB1);
    mlm[0][l] = mA; mlm[1][l] = lA; mlm[2][l] = mB; mlm[3][l] = lB;
  }
  __syncthreads();
  if (w == 0) {
    float pmA = mlm[0][l], plA = mlm[1][l], pmB = mlm[2][l], plB = mlm[3][l];
    float mSA = fmaxf(mA, pmA);
    float f0A = __builtin_amdgcn_exp2f(mA - mSA), f1A = __builtin_amdgcn_exp2f(pmA - mSA);
    lA = lA * f0A + plA * f1A;
    absorb(0, oA0, f0A, f1A); absorb(1, oA1, f0A, f1A);
    float mSB = fmaxf(mB, pmB);
    float f0B = __builtin_amdgcn_exp2f(mB - mSB), f1B = __builtin_amdgcn_exp2f(pmB - mSB);
    lB = lB * f0B + plB * f1B;
    absorb(2, oB0, f0B, f1B); absorb(3, oB1, f0B, f1B);

    const int b = bh >> 4, h = bh & 15;
    auto epi = [&](const f32x16& o0, const f32x16& o1, float lsum, int qrow) {
      const float inv = 1.0f / lsum;
      __bf16* obase = ob + ((size_t)b * T_SEQ + qrow) * D_MODEL + h * 64;
#pragma unroll
      for (int Q = 0; Q < 4; ++Q) {
        bf16x4 pk0, pk1;
#pragma unroll
        for (int e = 0; e < 4; ++e) {
          pk0[e] = (__bf16)(o0[Q * 4 + e] * inv);
          pk1[e] = (__bf16)(o1[Q * 4 + e] * inv);
        }
        *reinterpret_cast<bf16x4*>(obase + 8 * Q + 4 * hi) = pk0;
        *reinterpret_cast<bf16x4*>(obase + 32 + 8 * Q + 4 * hi) = pk1;
      }
    };
    epi(oA0, oA1, lA, qrowA);
    epi(oB0, oB1, lB, qrowB);
  }
}

extern "C" void kernel_launch(void* const* d_in, const int* in_sizes, int n_in,
                              void* d_out, int out_size, void* d_ws, size_t ws_size,
                              hipStream_t stream) {
  const float* x     = (const float*)d_in[0];
  const float* w_qkv = (const float*)d_in[1];
  const float* b_qkv = (const float*)d_in[2];
  const float* w_out = (const float*)d_in[3];
  const float* b_out = (const float*)d_in[4];
  const float* fc    = (const float*)d_in[5];
  const float* fs    = (const float*)d_in[6];
  float* out = (float*)d_out;
  char* ws = (char*)d_ws;

  __bf16* xb    = (__bf16*)(ws);
  __bf16* wqkvb = (__bf16*)(ws + 8388608);
  __bf16* woutb = (__bf16*)(ws + 14680064);
  __bf16* qbuf  = (__bf16*)(ws + 16777216);
  __bf16* kbuf  = (__bf16*)(ws + 25165824);
  __bf16* vtbuf = (__bf16*)(ws + 33554432);
  __bf16* attnb = xb;  // xb dead after gemm_qkv

  cvt_all<<<8192, 256, 0, stream>>>(x, w_qkv, w_out, xb, wqkvb, woutb);
  gemm_qkv<<<dim3(24, 32), 256, 0, stream>>>(xb, wqkvb, b_qkv, fc, fs, qbuf, kbuf, vtbuf);
  attn_fwd<<<1024, 128, 0, stream>>>(qbuf, kbuf, vtbuf, attnb);
  gemm_out<<<dim3(8, 32), 256, 0, stream>>>(attnb, woutb, b_out, out);
}

// Round 9
// 139.185 us; speedup vs baseline: 1.3310x; 1.0882x over previous
//
#include <hip/hip_runtime.h>

// ---- problem constants ----
#define T_SEQ 2048
#define D_MODEL 1024
#define N_HEADS 16
#define D_HEAD 64
#define NT 32          // T_SEQ / 64
#define K_DIM 1024

typedef __attribute__((ext_vector_type(8))) __bf16 bf16x8;
typedef __attribute__((ext_vector_type(4))) __bf16 bf16x4;
typedef __attribute__((ext_vector_type(4))) float f32x4;
typedef __attribute__((ext_vector_type(16))) float f32x16;

#define SCL_LOG2 0.180336880f  // 0.125 * log2(e)
#define MASKVAL (-1e30f)

#define GLOAD_LDS16(g, l)                                                     \
  __builtin_amdgcn_global_load_lds(                                           \
      (const __attribute__((address_space(1))) void*)(g),                     \
      (__attribute__((address_space(3))) void*)(l), 16, 0, 0)

// ---------------- fused f32 -> bf16 convert (x | w_qkv | w_out in one launch) ----------------
#define N4_X 1048576
#define N4_WQ 786432
#define N4_WO 262144
__global__ __launch_bounds__(256) void cvt_all(
    const float* __restrict__ x, const float* __restrict__ wq, const float* __restrict__ wo,
    __bf16* __restrict__ xb, __bf16* __restrict__ wqb, __bf16* __restrict__ wob) {
  int i = blockIdx.x * 256 + threadIdx.x;
  const float* src;
  __bf16* dst;
  int off;
  if (i < N4_X)             { src = x;  dst = xb;  off = i; }
  else if (i < N4_X + N4_WQ){ src = wq; dst = wqb; off = i - N4_X; }
  else                      { src = wo; dst = wob; off = i - (N4_X + N4_WQ); }
  float4 f = reinterpret_cast<const float4*>(src)[off];
  bf16x4 o;
  o[0] = (__bf16)f.x; o[1] = (__bf16)f.y; o[2] = (__bf16)f.z; o[3] = (__bf16)f.w;
  reinterpret_cast<bf16x4*>(dst)[off] = o;
}

// ---------------- QKV GEMM (m97 structure) + fused bias + RoPE ----------------
// q -> (BH,T,DK) bf16 (RoPE'd). K,V -> FRAGMENT-PACKED for attn's 32x32x16 MFMA:
//   kpk[(((bh*32+tile)*8 + a*4+kc)*64 + hi*32+l31)*8 + e]
//     where t = tile*64 + a*32 + l31, dk = kc*16 + hi*8 + e   (K, RoPE'd)
//   vpk[(((bh*32+tile)*8 + a*4+ks)*64 + hi*32+l31)*8 + e]
//     where t = tile*64 + ks*16 + hi*8 + e, dk = a*32 + l31
// so attn's per-fragment load is base + lane*16B (fully coalesced, 8 lines/instr).
__global__ __launch_bounds__(256) void gemm_qkv(
    const __bf16* __restrict__ A, const __bf16* __restrict__ W,
    const float* __restrict__ bias, const float* __restrict__ fc,
    const float* __restrict__ fs,
    __bf16* __restrict__ qb, __bf16* __restrict__ kpk, __bf16* __restrict__ vpk) {
  __shared__ __bf16 As[128 * 64];
  __shared__ __bf16 Bs[128 * 64];
  const int bm = blockIdx.y * 128, bn = blockIdx.x * 128;
  const int tid = threadIdx.x;
  const int w = tid >> 6, l = tid & 63;
  const int wr = w >> 1, wc = w & 1;
  const int l15 = l & 15, lg = l >> 4;
  const int srow = w * 32 + (l >> 3);
  const int scol = (l & 7) * 8;
  f32x4 acc[4][4] = {};
  for (int k0 = 0; k0 < K_DIM; k0 += 64) {
#pragma unroll
    for (int q = 0; q < 4; ++q) {
      GLOAD_LDS16(&A[(size_t)(bm + srow + q * 8) * K_DIM + k0 + scol], &As[(w * 32 + q * 8) * 64]);
      GLOAD_LDS16(&W[(size_t)(bn + srow + q * 8) * K_DIM + k0 + scol], &Bs[(w * 32 + q * 8) * 64]);
    }
    __syncthreads();
#pragma unroll
    for (int kk = 0; kk < 2; ++kk) {
      bf16x8 af[4], bfr[4];
#pragma unroll
      for (int i = 0; i < 4; ++i)
        af[i] = *reinterpret_cast<const bf16x8*>(&As[(wr * 64 + i * 16 + l15) * 64 + kk * 32 + lg * 8]);
#pragma unroll
      for (int j = 0; j < 4; ++j)
        bfr[j] = *reinterpret_cast<const bf16x8*>(&Bs[(wc * 64 + j * 16 + l15) * 64 + kk * 32 + lg * 8]);
      __builtin_amdgcn_s_setprio(1);
#pragma unroll
      for (int i = 0; i < 4; ++i)
#pragma unroll
        for (int j = 0; j < 4; ++j)
          acc[i][j] = __builtin_amdgcn_mfma_f32_16x16x32_bf16(af[i], bfr[j], acc[i][j], 0, 0, 0);
      __builtin_amdgcn_s_setprio(0);
    }
    __syncthreads();
  }
#pragma unroll
  for (int i = 0; i < 4; ++i)
#pragma unroll
    for (int j = 0; j < 4; ++j) {
      int n = bn + wc * 64 + j * 16 + l15;
      float bv = bias[n];
      int which = n >> 10, d = n & 1023;
      int h = d >> 6, dk = d & 63;
      int m0 = bm + wr * 64 + i * 16 + lg * 4;
      int b = m0 >> 11;
      int bh = b * N_HEADS + h;
      int t0_ = m0 & 2047;
      int tile = t0_ >> 6, tl0 = t0_ & 63;
      if (which == 2) {
        // V fragment-pack: 4 consecutive t land in one 16B chunk (e0 in {0,4})
        int ks = tl0 >> 4, hi2 = (tl0 >> 3) & 1, e0 = tl0 & 7;
        int adk = dk >> 5, l31v = dk & 31;
        bf16x4 pk;
#pragma unroll
        for (int r = 0; r < 4; ++r) pk[r] = (__bf16)(acc[i][j][r] + bv);
        size_t idx = (((size_t)bh * 32 + tile) * 8 + adk * 4 + ks) * 512 + (hi2 * 32 + l31v) * 8 + e0;
        *reinterpret_cast<bf16x4*>(&vpk[idx]) = pk;
      } else {
        int pi = dk >> 1;
        bool odd = dk & 1;
        if (which == 1) {
          // K: RoPE then fragment-pack (scalar stores, 16B stride across r)
          int a = tl0 >> 5, l31_0 = tl0 & 31;
          int kc = dk >> 4, hik = (dk >> 3) & 1, e = dk & 7;
          size_t base = (((size_t)bh * 32 + tile) * 8 + a * 4 + kc) * 512 + (hik * 32 + l31_0) * 8 + e;
#pragma unroll
          for (int r = 0; r < 4; ++r) {
            int t = t0_ + r;
            float v = acc[i][j][r] + bv;
            float part = __shfl_xor(v, 1);
            float c = fc[t * 32 + pi], s = fs[t * 32 + pi];
            float rv = odd ? (part * s + v * c) : (v * c - part * s);
            kpk[base + (size_t)r * 8] = (__bf16)rv;
          }
        } else {
#pragma unroll
          for (int r = 0; r < 4; ++r) {
            int t = t0_ + r;
            float v = acc[i][j][r] + bv;
            float part = __shfl_xor(v, 1);
            float c = fc[t * 32 + pi], s = fs[t * 32 + pi];
            float rv = odd ? (part * s + v * c) : (v * c - part * s);
            qb[((size_t)bh * T_SEQ + t) * D_HEAD + dk] = (__bf16)rv;
          }
        }
      }
    }
}

// ---------------- output GEMM: 128x64 tile (512 blocks, 2/CU) ----------------
__global__ __launch_bounds__(256) void gemm_out(
    const __bf16* __restrict__ A, const __bf16* __restrict__ W,
    const float* __restrict__ bias, float* __restrict__ out) {
  __shared__ __bf16 As[128 * 64];
  __shared__ __bf16 Bs[64 * 64];
  const int bm = blockIdx.y * 128, bn = blockIdx.x * 64;
  const int tid = threadIdx.x;
  const int w = tid >> 6, l = tid & 63;
  const int l15 = l & 15, lg = l >> 4;
  const int r8_ = l >> 3, c8 = (l & 7) * 8;
  f32x4 acc[2][4] = {};
  for (int k0 = 0; k0 < K_DIM; k0 += 64) {
#pragma unroll
    for (int q = 0; q < 4; ++q)
      GLOAD_LDS16(&A[(size_t)(bm + w * 32 + q * 8 + r8_) * K_DIM + k0 + c8], &As[(w * 32 + q * 8) * 64]);
#pragma unroll
    for (int q = 0; q < 2; ++q)
      GLOAD_LDS16(&W[(size_t)(bn + w * 16 + q * 8 + r8_) * K_DIM + k0 + c8], &Bs[(w * 16 + q * 8) * 64]);
    __syncthreads();
#pragma unroll
    for (int kk = 0; kk < 2; ++kk) {
      bf16x8 af[2], bfr[4];
#pragma unroll
      for (int i = 0; i < 2; ++i)
        af[i] = *reinterpret_cast<const bf16x8*>(&As[(w * 32 + i * 16 + l15) * 64 + kk * 32 + lg * 8]);
#pragma unroll
      for (int j = 0; j < 4; ++j)
        bfr[j] = *reinterpret_cast<const bf16x8*>(&Bs[(j * 16 + l15) * 64 + kk * 32 + lg * 8]);
      __builtin_amdgcn_s_setprio(1);
#pragma unroll
      for (int i = 0; i < 2; ++i)
#pragma unroll
        for (int j = 0; j < 4; ++j)
          acc[i][j] = __builtin_amdgcn_mfma_f32_16x16x32_bf16(af[i], bfr[j], acc[i][j], 0, 0, 0);
      __builtin_amdgcn_s_setprio(0);
    }
    __syncthreads();
  }
#pragma unroll
  for (int i = 0; i < 2; ++i)
#pragma unroll
    for (int j = 0; j < 4; ++j) {
      int n = bn + j * 16 + l15;
      float bv = bias[n];
#pragma unroll
      for (int r = 0; r < 4; ++r) {
        int m = bm + w * 32 + i * 16 + lg * 4 + r;
        out[(size_t)m * D_MODEL + n] = acc[i][j][r] + bv;
      }
    }
}

// ---------------- causal flash attention: coalesced fragment loads + split-K x2 ----------------
// 1024 blocks x 128 threads (2 waves). Block owns strip pair (stA=k, stB=63-k) of one
// bh; wave w processes KV tiles it = w, w+2, ... with private (m,l,o). K/V read from
// fragment-packed buffers: each load is base + lane*16B (contiguous 1KB, 8 cache lines)
// -- fixes the L1-tag-throughput wall of row-scattered loads. K prefetched 2 tiles ahead.
__global__ __launch_bounds__(128) void attn_fwd(
    const __bf16* __restrict__ qb, const __bf16* __restrict__ kpk,
    const __bf16* __restrict__ vpk, __bf16* __restrict__ ob) {
  __shared__ float osm[4][64][16];   // wave1 partial O, 16B chunks XOR'd by lane&3
  __shared__ float mlm[4][64];       // wave1 {mA,lA,mB,lB}
  const int g = blockIdx.x;
  const int xcd = g & 7, s = g >> 3;              // s in [0,128)
  const int bh = xcd * 4 + (s & 3);               // 4 heads per XCD for L2 locality
  const int k = s >> 2;                           // pair id in [0,32)
  const int w = threadIdx.x >> 6, l = threadIdx.x & 63;
  const int stA = k, stB = 63 - k;
  const int vA = (stA >> 1) + 1, vB = (stB >> 1) + 1;   // KV tiles per strip
  const int sbA = stA * 32, sbB = stB * 32;
  const int l31 = l & 31, hi = l >> 5;
  const int qrowA = sbA + l31, qrowB = sbB + l31;

  // Q B-fragments: lane holds col=qrow, k=dk = kc*16 + hi*8 + j
  bf16x8 qfA[4], qfB[4];
  {
    const __bf16* qp = qb + ((size_t)bh * T_SEQ + qrowA) * D_HEAD + hi * 8;
#pragma unroll
    for (int kc = 0; kc < 4; ++kc) qfA[kc] = *reinterpret_cast<const bf16x8*>(qp + kc * 16);
  }
  {
    const __bf16* qp = qb + ((size_t)bh * T_SEQ + qrowB) * D_HEAD + hi * 8;
#pragma unroll
    for (int kc = 0; kc < 4; ++kc) qfB[kc] = *reinterpret_cast<const bf16x8*>(qp + kc * 16);
  }
  f32x16 oA0 = {}, oA1 = {}, oB0 = {}, oB1 = {};
  float mA = MASKVAL, lA = 0.f, mB = MASKVAL, lB = 0.f;

  // fragment-packed bases: per bh 32 tiles * 8 frags * 512 elems
  const __bf16* kpbase = kpk + (size_t)bh * 131072 + (size_t)l * 8;
  const __bf16* vpbase = vpk + (size_t)bh * 131072 + (size_t)l * 8;

  auto loadK = [&](bf16x8* dst, int t0) {
    const __bf16* p = kpbase + (size_t)(t0 >> 6) * 4096;
#pragma unroll
    for (int f = 0; f < 8; ++f)
      dst[f] = *reinterpret_cast<const bf16x8*>(p + f * 512);
  };
  auto loadV = [&](bf16x8* dst, int t0) {
    const __bf16* p = vpbase + (size_t)(t0 >> 6) * 4096;
#pragma unroll
    for (int f = 0; f < 8; ++f)
      dst[f] = *reinterpret_cast<const bf16x8*>(p + f * 512);
  };

  auto process = [&](const bf16x8* kf, const bf16x8* vf, const bf16x8* qf,
                     f32x16& o0, f32x16& o1, float& m, float& lsum,
                     int sb, int t0) {
    f32x16 sa0 = {}, sa1 = {};
    __builtin_amdgcn_s_setprio(1);
#pragma unroll
    for (int kc = 0; kc < 4; ++kc) {
      sa0 = __builtin_amdgcn_mfma_f32_32x32x16_bf16(kf[kc], qf[kc], sa0, 0, 0, 0);
      sa1 = __builtin_amdgcn_mfma_f32_32x32x16_bf16(kf[4 + kc], qf[kc], sa1, 0, 0, 0);
    }
    __builtin_amdgcn_s_setprio(0);

    float sv[32];
    if (t0 + 63 <= sb) {
#pragma unroll
      for (int r = 0; r < 16; ++r) { sv[r] = sa0[r]; sv[16 + r] = sa1[r]; }
    } else {
      int thr = sb + l31 - t0 - 4 * hi;
#pragma unroll
      for (int r = 0; r < 16; ++r) {
        int kc0 = (r & 3) + 8 * (r >> 2);
        sv[r]      = (kc0 <= thr) ? sa0[r] : MASKVAL;
        sv[16 + r] = (kc0 + 32 <= thr) ? sa1[r] : MASKVAL;
      }
    }
    float m0 = sv[0], m1 = sv[1], m2 = sv[2], m3 = sv[3];
#pragma unroll
    for (int i = 4; i < 32; i += 4) {
      m0 = fmaxf(m0, sv[i]); m1 = fmaxf(m1, sv[i + 1]);
      m2 = fmaxf(m2, sv[i + 2]); m3 = fmaxf(m3, sv[i + 3]);
    }
    float mx = fmaxf(fmaxf(m0, m1), fmaxf(m2, m3));
    mx = fmaxf(mx, __shfl_xor(mx, 32));
    float mnew = fmaxf(m, mx * SCL_LOG2);
    float fac = __builtin_amdgcn_exp2f(m - mnew);
    m = mnew;
    float s0 = 0.f, s1 = 0.f, s2 = 0.f, s3 = 0.f;
#pragma unroll
    for (int i = 0; i < 32; i += 4) {
      sv[i]     = __builtin_amdgcn_exp2f(__builtin_fmaf(sv[i],     SCL_LOG2, -mnew)); s0 += sv[i];
      sv[i + 1] = __builtin_amdgcn_exp2f(__builtin_fmaf(sv[i + 1], SCL_LOG2, -mnew)); s1 += sv[i + 1];
      sv[i + 2] = __builtin_amdgcn_exp2f(__builtin_fmaf(sv[i + 2], SCL_LOG2, -mnew)); s2 += sv[i + 2];
      sv[i + 3] = __builtin_amdgcn_exp2f(__builtin_fmaf(sv[i + 3], SCL_LOG2, -mnew)); s3 += sv[i + 3];
    }
    float sum = (s0 + s1) + (s2 + s3);
    sum += __shfl_xor(sum, 32);
    lsum = lsum * fac + sum;
    o0 *= fac;
    o1 *= fac;

#pragma unroll
    for (int kb4 = 0; kb4 < 4; ++kb4) {
      unsigned int c0, c1, c2, c3;
      asm("v_cvt_pk_bf16_f32 %0, %1, %2" : "=v"(c0) : "v"(sv[kb4 * 8 + 0]), "v"(sv[kb4 * 8 + 1]));
      asm("v_cvt_pk_bf16_f32 %0, %1, %2" : "=v"(c1) : "v"(sv[kb4 * 8 + 2]), "v"(sv[kb4 * 8 + 3]));
      asm("v_cvt_pk_bf16_f32 %0, %1, %2" : "=v"(c2) : "v"(sv[kb4 * 8 + 4]), "v"(sv[kb4 * 8 + 5]));
      asm("v_cvt_pk_bf16_f32 %0, %1, %2" : "=v"(c3) : "v"(sv[kb4 * 8 + 6]), "v"(sv[kb4 * 8 + 7]));
      unsigned int p0 = (unsigned)__shfl_xor((int)c0, 32);
      unsigned int p1 = (unsigned)__shfl_xor((int)c1, 32);
      unsigned int p2 = (unsigned)__shfl_xor((int)c2, 32);
      unsigned int p3 = (unsigned)__shfl_xor((int)c3, 32);
      union { unsigned int u[4]; bf16x8 v; } cv;
      cv.u[0] = hi ? p2 : c0;
      cv.u[1] = hi ? p3 : c1;
      cv.u[2] = hi ? c2 : p0;
      cv.u[3] = hi ? c3 : p1;
      __builtin_amdgcn_s_setprio(1);
      o0 = __builtin_amdgcn_mfma_f32_32x32x16_bf16(vf[kb4], cv.v, o0, 0, 0, 0);
      o1 = __builtin_amdgcn_mfma_f32_32x32x16_bf16(vf[4 + kb4], cv.v, o1, 0, 0, 0);
      __builtin_amdgcn_s_setprio(0);
    }
  };

  // ---- main loop: this wave's tiles it = w, w+2, ...; K ping-pong 2 ahead ----
  bf16x8 kf0[8], kf1[8], vf[8];
  loadK(kf0, w * 64);
  int it = w;
  while (true) {
    int t0 = it * 64;
    loadV(vf, t0);
    if (it + 2 < vB) loadK(kf1, t0 + 128);
    process(kf0, vf, qfB, oB0, oB1, mB, lB, sbB, t0);
    if (it < vA) process(kf0, vf, qfA, oA0, oA1, mA, lA, sbA, t0);
    it += 2;
    if (it >= vB) break;
    t0 = it * 64;
    loadV(vf, t0);
    if (it + 2 < vB) loadK(kf0, t0 + 128);
    process(kf1, vf, qfB, oB0, oB1, mB, lB, sbB, t0);
    if (it < vA) process(kf1, vf, qfA, oA0, oA1, mA, lA, sbA, t0);
    it += 2;
    if (it >= vB) break;
  }

  // ---- split-K merge: wave1 publishes, wave0 merges exactly and writes ----
  auto publish = [&](int buf, const f32x16& o) {
#pragma unroll
    for (int c = 0; c < 4; ++c) {
      f32x4 ch;
      ch[0] = o[c * 4 + 0]; ch[1] = o[c * 4 + 1];
      ch[2] = o[c * 4 + 2]; ch[3] = o[c * 4 + 3];
      *reinterpret_cast<f32x4*>(&osm[buf][l][(c ^ (l & 3)) * 4]) = ch;
    }
  };
  auto absorb = [&](int buf, f32x16& o, float f0, float f1) {
#pragma unroll
    for (int c = 0; c < 4; ++c) {
      f32x4 ch = *reinterpret_cast<const f32x4*>(&osm[buf][l][(c ^ (l & 3)) * 4]);
#pragma unroll
      for (int e = 0; e < 4; ++e) o[c * 4 + e] = o[c * 4 + e] * f0 + ch[e] * f1;
    }
  };
  if (w == 1) {
    publish(0, oA0); publish(1, oA1); publish(2, oB0); publish(3, oB1);
    mlm[0][l] = mA; mlm[1][l] = lA; mlm[2][l] = mB; mlm[3][l] = lB;
  }
  __syncthreads();
  if (w == 0) {
    float pmA = mlm[0][l], plA = mlm[1][l], pmB = mlm[2][l], plB = mlm[3][l];
    float mSA = fmaxf(mA, pmA);
    float f0A = __builtin_amdgcn_exp2f(mA - mSA), f1A = __builtin_amdgcn_exp2f(pmA - mSA);
    lA = lA * f0A + plA * f1A;
    absorb(0, oA0, f0A, f1A); absorb(1, oA1, f0A, f1A);
    float mSB = fmaxf(mB, pmB);
    float f0B = __builtin_amdgcn_exp2f(mB - mSB), f1B = __builtin_amdgcn_exp2f(pmB - mSB);
    lB = lB * f0B + plB * f1B;
    absorb(2, oB0, f0B, f1B); absorb(3, oB1, f0B, f1B);

    const int b = bh >> 4, h = bh & 15;
    auto epi = [&](const f32x16& o0, const f32x16& o1, float lsum, int qrow) {
      const float inv = 1.0f / lsum;
      __bf16* obase = ob + ((size_t)b * T_SEQ + qrow) * D_MODEL + h * 64;
#pragma unroll
      for (int Q = 0; Q < 4; ++Q) {
        bf16x4 pk0, pk1;
#pragma unroll
        for (int e = 0; e < 4; ++e) {
          pk0[e] = (__bf16)(o0[Q * 4 + e] * inv);
          pk1[e] = (__bf16)(o1[Q * 4 + e] * inv);
        }
        *reinterpret_cast<bf16x4*>(obase + 8 * Q + 4 * hi) = pk0;
        *reinterpret_cast<bf16x4*>(obase + 32 + 8 * Q + 4 * hi) = pk1;
      }
    };
    epi(oA0, oA1, lA, qrowA);
    epi(oB0, oB1, lB, qrowB);
  }
}

extern "C" void kernel_launch(void* const* d_in, const int* in_sizes, int n_in,
                              void* d_out, int out_size, void* d_ws, size_t ws_size,
                              hipStream_t stream) {
  const float* x     = (const float*)d_in[0];
  const float* w_qkv = (const float*)d_in[1];
  const float* b_qkv = (const float*)d_in[2];
  const float* w_out = (const float*)d_in[3];
  const float* b_out = (const float*)d_in[4];
  const float* fc    = (const float*)d_in[5];
  const float* fs    = (const float*)d_in[6];
  float* out = (float*)d_out;
  char* ws = (char*)d_ws;

  __bf16* xb    = (__bf16*)(ws);
  __bf16* wqkvb = (__bf16*)(ws + 8388608);
  __bf16* woutb = (__bf16*)(ws + 14680064);
  __bf16* qbuf  = (__bf16*)(ws + 16777216);
  __bf16* kpk   = (__bf16*)(ws + 25165824);
  __bf16* vpk   = (__bf16*)(ws + 33554432);
  __bf16* attnb = xb;  // xb dead after gemm_qkv

  cvt_all<<<8192, 256, 0, stream>>>(x, w_qkv, w_out, xb, wqkvb, woutb);
  gemm_qkv<<<dim3(24, 32), 256, 0, stream>>>(xb, wqkvb, b_qkv, fc, fs, qbuf, kpk, vpk);
  attn_fwd<<<1024, 128, 0, stream>>>(qbuf, kpk, vpk, attnb);
  gemm_out<<<dim3(16, 32), 256, 0, stream>>>(attnb, woutb, b_out, out);
}